// Round 9
// baseline (179.269 us; speedup 1.0000x reference)
//
#include <hip/hip_runtime.h>
#include <math.h>

// ---------------------------------------------------------------------------
// ClustGeoNodeEncoder via two-level bucket decomposition.
//
// Measured walls: global atomics ~16-23 G ops/s (r2-r4); LDS-atomic moments at
// low parallelism serialize (r5); per-wave redundant f64 eigen is VALU-heavy
// (r6); splitting buckets across blocks kills gather line-locality (r7);
// double-gather + 384KB windows thrash per-XCD L2 (r8: 268MB fetch, 2.7TB/s).
// Design (r9):
//   p1_bucket   : bucket = cid>>6 (782 buckets, 64 clusters each). Per 4096-
//                 voxel round: LDS ds_add_rtn local ranks + <=782 returning
//                 global atomics allocate bucket space; scatter float4 ->
//                 bbuf, low-6-bit cid byte -> lcb.
//   p2_features : 1 block (512 thr) per bucket; 96KB window.
//                 A: hist+scan+counting-sort indices (reads lcb bytes only)
//                 B: 8 waves x 8 clusters: gather <=128 pts/cluster into
//                    REGISTERS (2 float4/cluster, statically indexed),
//                    shuffle-reduce 9 moments -> LDS
//                 C: 64-lane f64 eigen -> out[0..2], cen/v0/dirwt -> LDS
//                 D: sc from the HELD registers (no re-gather) -> out[3]
// Fallback (small ws): round-2 packed u64 fixed-point pipeline.
// ---------------------------------------------------------------------------

#define NB_CL   64         // clusters per bucket
#define CAP2    6144       // per-bucket point capacity (mean 5120, +14 sigma)
#define NB_MAX  1024       // max buckets supported by p1's LDS histogram

// ========================= shared: 3x3 symmetric eigen =====================
__device__ inline void eig3_sym(double a00, double a01, double a02,
                                double a11, double a12, double a22,
                                double& w0, double& w1, double& w2,
                                double v[3]) {
    double p1 = a01 * a01 + a02 * a02 + a12 * a12;
    double q  = (a00 + a11 + a22) / 3.0;
    double d0 = a00 - q, d1 = a11 - q, d2 = a22 - q;
    double p2 = d0 * d0 + d1 * d1 + d2 * d2 + 2.0 * p1;
    double p  = sqrt(p2 / 6.0);
    if (p < 1e-300) {
        w0 = w1 = w2 = q;
        v[0] = 0.0; v[1] = 0.0; v[2] = 1.0;
        return;
    }
    double ip = 1.0 / p;
    double b00 = d0 * ip, b11 = d1 * ip, b22 = d2 * ip;
    double b01 = a01 * ip, b02 = a02 * ip, b12 = a12 * ip;
    double detB = b00 * (b11 * b22 - b12 * b12)
                - b01 * (b01 * b22 - b12 * b02)
                + b02 * (b01 * b12 - b11 * b02);
    double r = detB * 0.5;
    r = fmin(1.0, fmax(-1.0, r));
    double phi = acos(r) / 3.0;
    w2 = q + 2.0 * p * cos(phi);
    w0 = q + 2.0 * p * cos(phi + 2.0943951023931953);  // +2*pi/3
    w1 = 3.0 * q - w2 - w0;

    double r0x = a00 - w2, r0y = a01,       r0z = a02;
    double r1x = a01,      r1y = a11 - w2,  r1z = a12;
    double r2x = a02,      r2y = a12,       r2z = a22 - w2;

    double c0x = r0y * r1z - r0z * r1y;
    double c0y = r0z * r1x - r0x * r1z;
    double c0z = r0x * r1y - r0y * r1x;
    double n0  = c0x * c0x + c0y * c0y + c0z * c0z;

    double c1x = r0y * r2z - r0z * r2y;
    double c1y = r0z * r2x - r0x * r2z;
    double c1z = r0x * r2y - r0y * r2x;
    double n1  = c1x * c1x + c1y * c1y + c1z * c1z;

    double c2x = r1y * r2z - r1z * r2y;
    double c2y = r1z * r2x - r1x * r2z;
    double c2z = r1x * r2y - r1y * r2x;
    double n2  = c2x * c2x + c2y * c2y + c2z * c2z;

    double vx, vy, vz, nn;
    if (n0 >= n1 && n0 >= n2) { vx = c0x; vy = c0y; vz = c0z; nn = n0; }
    else if (n1 >= n2)        { vx = c1x; vy = c1y; vz = c1z; nn = n1; }
    else                      { vx = c2x; vy = c2y; vz = c2z; nn = n2; }
    if (nn < 1e-300) {
        v[0] = 0.0; v[1] = 0.0; v[2] = 1.0;
        return;
    }
    double inv = rsqrt(nn);
    v[0] = vx * inv; v[1] = vy * inv; v[2] = vz * inv;
}

// ============================ primary path =================================
#define P1_BLOCK 1024
#define P1_ITEMS 4     // voxels per thread per round -> 4096 per block-round

__global__ void p1_bucket(const float* __restrict__ data,
                          const int* __restrict__ cid,
                          unsigned int* __restrict__ gcnt,     // [nbuckets]
                          float4* __restrict__ bbuf,           // [nb*CAP2]
                          unsigned char* __restrict__ lcb,     // [nb*CAP2]
                          int n_vox, int nbuckets) {
    __shared__ unsigned int hist[NB_MAX];
    __shared__ unsigned int base[NB_MAX];
    const int tid = threadIdx.x;
    const int per_round = P1_BLOCK * P1_ITEMS;
    const int total_rounds = (n_vox + per_round - 1) / per_round;

    for (int r = blockIdx.x; r < total_rounds; r += gridDim.x) {
        const int start = r * per_round;
        for (int j = tid; j < nbuckets; j += P1_BLOCK) hist[j] = 0;
        __syncthreads();

        int   bk[P1_ITEMS];
        int   cd[P1_ITEMS];
        float px[P1_ITEMS], py[P1_ITEMS], pz[P1_ITEMS];
        unsigned int rk[P1_ITEMS];
#pragma unroll
        for (int k = 0; k < P1_ITEMS; ++k) {
            int i = start + tid + k * P1_BLOCK;   // coalesced lane pattern
            if (i < n_vox) {
                int c = cid[i];
                cd[k] = c;
                bk[k] = c >> 6;
                const float* row = data + (size_t)i * 6;
                px[k] = row[1]; py[k] = row[2]; pz[k] = row[3];
                rk[k] = atomicAdd(&hist[bk[k]], 1u);   // local rank
            } else {
                bk[k] = -1;
            }
        }
        __syncthreads();
        for (int j = tid; j < nbuckets; j += P1_BLOCK) {
            unsigned int h = hist[j];
            base[j] = h ? atomicAdd(&gcnt[j], h) : 0u;
        }
        __syncthreads();
#pragma unroll
        for (int k = 0; k < P1_ITEMS; ++k) {
            if (bk[k] >= 0) {
                unsigned int pos = base[bk[k]] + rk[k];
                if (pos < (unsigned int)CAP2) {
                    bbuf[(size_t)bk[k] * CAP2 + pos] =
                        make_float4(px[k], py[k], pz[k], 0.0f);
                    lcb[(size_t)bk[k] * CAP2 + pos] =
                        (unsigned char)(cd[k] & (NB_CL - 1));
                }
            }
        }
        __syncthreads();
    }
}

__global__ __launch_bounds__(512) void p2_features(
        const unsigned int* __restrict__ gcnt,
        const float4* __restrict__ bbuf,
        const unsigned char* __restrict__ lcb,
        float* __restrict__ out, int C) {
    __shared__ unsigned int hist[NB_CL];
    __shared__ unsigned int basex[NB_CL];
    __shared__ unsigned int hist2[NB_CL];
    __shared__ unsigned short idx16[CAP2];      // 12 KB
    __shared__ float mom[9][NB_CL];
    __shared__ float cenl[3][NB_CL], vvl[3][NB_CL], dwl[NB_CL];

    const int b   = blockIdx.x;
    const int tid = threadIdx.x;
    const int bcnt = min((int)gcnt[b], CAP2);
    const float4* src = bbuf + (size_t)b * CAP2;
    const unsigned char* lc8 = lcb + (size_t)b * CAP2;

    if (tid < NB_CL) { hist[tid] = 0; hist2[tid] = 0; }
    __syncthreads();

    // ---- A1: histogram from byte array (uchar4 loads) ----
    const int n4 = (bcnt + 3) >> 2;
    for (int g = tid; g < n4; g += 512) {
        uchar4 c4 = *reinterpret_cast<const uchar4*>(lc8 + 4 * g);
        int i = 4 * g;
        if (i + 0 < bcnt) atomicAdd(&hist[c4.x], 1u);
        if (i + 1 < bcnt) atomicAdd(&hist[c4.y], 1u);
        if (i + 2 < bcnt) atomicAdd(&hist[c4.z], 1u);
        if (i + 3 < bcnt) atomicAdd(&hist[c4.w], 1u);
    }
    __syncthreads();

    // ---- exclusive scan over 64 entries (wave 0 shfl scan) ----
    if (tid < NB_CL) {
        unsigned int h = hist[tid];
        unsigned int inc = h;
#pragma unroll
        for (int off = 1; off < NB_CL; off <<= 1) {
            unsigned int t = __shfl_up(inc, off);
            if (tid >= off) inc += t;
        }
        basex[tid] = inc - h;
    }
    __syncthreads();

    // ---- A2: counting-sort indices (byte reads again) ----
    for (int g = tid; g < n4; g += 512) {
        uchar4 c4 = *reinterpret_cast<const uchar4*>(lc8 + 4 * g);
        int i = 4 * g;
        if (i + 0 < bcnt) { unsigned int rk = atomicAdd(&hist2[c4.x], 1u); idx16[basex[c4.x] + rk] = (unsigned short)(i + 0); }
        if (i + 1 < bcnt) { unsigned int rk = atomicAdd(&hist2[c4.y], 1u); idx16[basex[c4.y] + rk] = (unsigned short)(i + 1); }
        if (i + 2 < bcnt) { unsigned int rk = atomicAdd(&hist2[c4.z], 1u); idx16[basex[c4.z] + rk] = (unsigned short)(i + 2); }
        if (i + 3 < bcnt) { unsigned int rk = atomicAdd(&hist2[c4.w], 1u); idx16[basex[c4.w] + rk] = (unsigned short)(i + 3); }
    }
    __syncthreads();

    const int w    = tid >> 6;     // 0..7
    const int lane = tid & 63;

    // ---- B: gather into registers + moments (single HBM gather) ----
    float4 qa0, qa1, qa2, qa3, qa4, qa5, qa6, qa7;   // first 64 pts / cluster
    float4 qb0, qb1, qb2, qb3, qb4, qb5, qb6, qb7;   // pts 64..127 / cluster
    int    nn[8];
    unsigned int nbs[8];

#define GATHER_MOM(JJ, QA, QB)                                                \
    {                                                                         \
        const int lc = (w << 3) | JJ;                                         \
        const int n  = (int)hist[lc];                                         \
        const unsigned int nb = basex[lc];                                    \
        nn[JJ] = n; nbs[JJ] = nb;                                             \
        float4 z = make_float4(0.f, 0.f, 0.f, 0.f);                           \
        QA = z; QB = z;                                                       \
        if (lane < n)      QA = src[idx16[nb + lane]];                        \
        if (lane + 64 < n) QB = src[idx16[nb + lane + 64]];                   \
        float s0 = QA.x + QB.x;                                               \
        float s1 = QA.y + QB.y;                                               \
        float s2 = QA.z + QB.z;                                               \
        float s3 = QA.x * QA.x + QB.x * QB.x;                                 \
        float s4 = QA.x * QA.y + QB.x * QB.y;                                 \
        float s5 = QA.x * QA.z + QB.x * QB.z;                                 \
        float s6 = QA.y * QA.y + QB.y * QB.y;                                 \
        float s7 = QA.y * QA.z + QB.y * QB.z;                                 \
        float s8 = QA.z * QA.z + QB.z * QB.z;                                 \
        for (int j = lane + 128; j < n; j += 64) {   /* rare n>128 tail */    \
            float4 p = src[idx16[nb + j]];                                    \
            s0 += p.x;       s1 += p.y;       s2 += p.z;                      \
            s3 += p.x * p.x; s4 += p.x * p.y; s5 += p.x * p.z;                \
            s6 += p.y * p.y; s7 += p.y * p.z; s8 += p.z * p.z;                \
        }                                                                     \
        _Pragma("unroll")                                                     \
        for (int d = 32; d > 0; d >>= 1) {                                    \
            s0 += __shfl_xor(s0, d); s1 += __shfl_xor(s1, d);                 \
            s2 += __shfl_xor(s2, d); s3 += __shfl_xor(s3, d);                 \
            s4 += __shfl_xor(s4, d); s5 += __shfl_xor(s5, d);                 \
            s6 += __shfl_xor(s6, d); s7 += __shfl_xor(s7, d);                 \
            s8 += __shfl_xor(s8, d);                                          \
        }                                                                     \
        if (lane == 0) {                                                      \
            mom[0][lc] = s0; mom[1][lc] = s1; mom[2][lc] = s2;                \
            mom[3][lc] = s3; mom[4][lc] = s4; mom[5][lc] = s5;                \
            mom[6][lc] = s6; mom[7][lc] = s7; mom[8][lc] = s8;                \
        }                                                                     \
    }

    GATHER_MOM(0, qa0, qb0)
    GATHER_MOM(1, qa1, qb1)
    GATHER_MOM(2, qa2, qb2)
    GATHER_MOM(3, qa3, qb3)
    GATHER_MOM(4, qa4, qb4)
    GATHER_MOM(5, qa5, qb5)
    GATHER_MOM(6, qa6, qb6)
    GATHER_MOM(7, qa7, qb7)
#undef GATHER_MOM
    __syncthreads();

    // ---- C: lane-per-cluster f64 eigen (64 lanes) ----
    if (tid < NB_CL) {
        const int t  = tid;
        const int cl = b * NB_CL + t;
        if (cl < C) {
            const int n = (int)hist[t];
            double dn = (double)n;
            double nd = (double)max(n, 1);
            double cx = (double)mom[0][t] / nd;
            double cy = (double)mom[1][t] / nd;
            double cz = (double)mom[2][t] / nd;

            double axx = (double)mom[3][t] - dn * cx * cx;
            double axy = (double)mom[4][t] - dn * cx * cy;
            double axz = (double)mom[5][t] - dn * cx * cz;
            double ayy = (double)mom[6][t] - dn * cy * cy;
            double ayz = (double)mom[7][t] - dn * cy * cz;
            double azz = (double)mom[8][t] - dn * cz * cz;

            double w0, w1, w2, v[3];
            eig3_sym(axx, axy, axz, ayy, ayz, azz, w0, w1, w2, v);

            double safe_w2 = (w2 > 0.0) ? w2 : 1.0;
            double isw = 1.0 / safe_w2;
            bool multi = (n >= 2);

            float fcx = (float)cx, fcy = (float)cy, fcz = (float)cz;
            float b3  = multi ? (float)(axx * isw) : 0.0f;
            float b4  = multi ? (float)(axy * isw) : 0.0f;
            float b5  = multi ? (float)(axz * isw) : 0.0f;
            float b7  = multi ? (float)(ayy * isw) : 0.0f;
            float b8  = multi ? (float)(ayz * isw) : 0.0f;
            float b11 = multi ? (float)(azz * isw) : 0.0f;

            float4* o = (float4*)(out + (size_t)cl * 16);
            o[0] = make_float4(fcx, fcy, fcz, b3);
            o[1] = make_float4(b4, b5, b4, b7);
            o[2] = make_float4(b8, b5, b8, b11);

            cenl[0][t] = fcx; cenl[1][t] = fcy; cenl[2][t] = fcz;
            vvl[0][t] = (float)v[0]; vvl[1][t] = (float)v[1]; vvl[2][t] = (float)v[2];
            dwl[t] = (float)(1.0 - w1 / safe_w2);
        }
    }
    __syncthreads();

    // ---- D: sc from held registers (tail re-gathers from L2) ----
#define SC_PASS(JJ, QA, QB)                                                   \
    {                                                                         \
        const int lc = (w << 3) | JJ;                                         \
        const int cl = b * NB_CL + lc;                                        \
        if (cl < C) {                                                         \
            const int n = nn[JJ];                                             \
            const unsigned int nb = nbs[JJ];                                  \
            const float fcx = cenl[0][lc], fcy = cenl[1][lc], fcz = cenl[2][lc];\
            const float vx = vvl[0][lc], vy = vvl[1][lc], vz = vvl[2][lc];    \
            float sc = 0.0f;                                                  \
            if (lane < n) {                                                   \
                float x = QA.x - fcx, y = QA.y - fcy, z = QA.z - fcz;         \
                float x0 = x * vx + y * vy + z * vz;                          \
                float qx = x - x0 * vx, qy = y - x0 * vy, qz = z - x0 * vz;   \
                sc += x0 * sqrtf(qx * qx + qy * qy + qz * qz);                \
            }                                                                 \
            if (lane + 64 < n) {                                              \
                float x = QB.x - fcx, y = QB.y - fcy, z = QB.z - fcz;         \
                float x0 = x * vx + y * vy + z * vz;                          \
                float qx = x - x0 * vx, qy = y - x0 * vy, qz = z - x0 * vz;   \
                sc += x0 * sqrtf(qx * qx + qy * qy + qz * qz);                \
            }                                                                 \
            for (int j = lane + 128; j < n; j += 64) {                        \
                float4 p = src[idx16[nb + j]];                                \
                float x = p.x - fcx, y = p.y - fcy, z = p.z - fcz;            \
                float x0 = x * vx + y * vy + z * vz;                          \
                float qx = x - x0 * vx, qy = y - x0 * vy, qz = z - x0 * vz;   \
                sc += x0 * sqrtf(qx * qx + qy * qy + qz * qz);                \
            }                                                                 \
            _Pragma("unroll")                                                 \
            for (int d = 32; d > 0; d >>= 1) sc += __shfl_xor(sc, d);         \
            if (lane == 0) {                                                  \
                float sgn = (sc < 0.0f) ? -1.0f : 1.0f;                       \
                float m = (n >= 2) ? sgn * dwl[lc] : 0.0f;                    \
                ((float4*)(out + (size_t)cl * 16))[3] =                       \
                    make_float4(vx * m, vy * m, vz * m, (float)n);            \
            }                                                                 \
        }                                                                     \
    }

    SC_PASS(0, qa0, qb0)
    SC_PASS(1, qa1, qb1)
    SC_PASS(2, qa2, qb2)
    SC_PASS(3, qa3, qb3)
    SC_PASS(4, qa4, qb4)
    SC_PASS(5, qa5, qb5)
    SC_PASS(6, qa6, qb6)
    SC_PASS(7, qa7, qb7)
#undef SC_PASS
}

// ============================ fallback path (round-2) ======================
#define FXP_SCALE 131072.0f
#define FXP_BIAS  4194304
#define FXP_INV   (1.0 / 131072.0)

__device__ __forceinline__ unsigned int fxp_enc(float v) {
    return (unsigned int)(__float2int_rn(v * FXP_SCALE) + FXP_BIAS);
}
__device__ __forceinline__ double fxp_dec(unsigned int s, int n) {
    return (double)((long long)s - (long long)n * FXP_BIAS) * FXP_INV;
}

__global__ void k1_accum(const float* __restrict__ data,
                         const int* __restrict__ cid,
                         unsigned long long* __restrict__ acc,
                         int n_vox) {
    int stride = gridDim.x * blockDim.x;
    for (int i = blockIdx.x * blockDim.x + threadIdx.x; i < n_vox; i += stride) {
        int c = cid[i];
        const float* row = data + (size_t)i * 6;
        float x = row[1], y = row[2], z = row[3];
        unsigned long long* a = acc + (size_t)c * 5;
        unsigned long long p0 = ((unsigned long long)fxp_enc(y)     << 32) | fxp_enc(x);
        unsigned long long p1 = ((unsigned long long)fxp_enc(x * x) << 32) | fxp_enc(z);
        unsigned long long p2 = ((unsigned long long)fxp_enc(x * z) << 32) | fxp_enc(x * y);
        unsigned long long p3 = ((unsigned long long)fxp_enc(y * z) << 32) | fxp_enc(y * y);
        unsigned long long p4 = (1ULL << 32)                               | fxp_enc(z * z);
        atomicAdd(&a[0], p0);
        atomicAdd(&a[1], p1);
        atomicAdd(&a[2], p2);
        atomicAdd(&a[3], p3);
        atomicAdd(&a[4], p4);
    }
}

__global__ void k2_cluster(const unsigned long long* __restrict__ acc,
                           float* __restrict__ wf,
                           float* __restrict__ out, int C) {
    int c = blockIdx.x * blockDim.x + threadIdx.x;
    if (c >= C) return;
    const unsigned long long* a = acc + (size_t)c * 5;
    unsigned long long s0 = a[0], s1 = a[1], s2 = a[2], s3 = a[3], s4 = a[4];
    int n = (int)(s4 >> 32);

    double sx  = fxp_dec((unsigned int)s0,         n);
    double sy  = fxp_dec((unsigned int)(s0 >> 32), n);
    double sz  = fxp_dec((unsigned int)s1,         n);
    double sxx = fxp_dec((unsigned int)(s1 >> 32), n);
    double sxy = fxp_dec((unsigned int)s2,         n);
    double sxz = fxp_dec((unsigned int)(s2 >> 32), n);
    double syy = fxp_dec((unsigned int)s3,         n);
    double syz = fxp_dec((unsigned int)(s3 >> 32), n);
    double szz = fxp_dec((unsigned int)s4,         n);

    double nd = (double)max(n, 1);
    double cx = sx / nd, cy = sy / nd, cz = sz / nd;
    double dn = (double)n;
    double axx = sxx - dn * cx * cx;
    double axy = sxy - dn * cx * cy;
    double axz = sxz - dn * cx * cz;
    double ayy = syy - dn * cy * cy;
    double ayz = syz - dn * cy * cz;
    double azz = szz - dn * cz * cz;

    double w0, w1, w2, v[3];
    eig3_sym(axx, axy, axz, ayy, ayz, azz, w0, w1, w2, v);

    double safe_w2 = (w2 > 0.0) ? w2 : 1.0;
    double dirwt   = 1.0 - w1 / safe_w2;
    double isw     = 1.0 / safe_w2;
    bool multi = (n >= 2);

    float* o = out + (size_t)c * 16;
    o[0] = (float)cx; o[1] = (float)cy; o[2] = (float)cz;
    if (multi) {
        o[3]  = (float)(axx * isw); o[4]  = (float)(axy * isw); o[5]  = (float)(axz * isw);
        o[6]  = (float)(axy * isw); o[7]  = (float)(ayy * isw); o[8]  = (float)(ayz * isw);
        o[9]  = (float)(axz * isw); o[10] = (float)(ayz * isw); o[11] = (float)(azz * isw);
    } else {
        o[3] = 0.f; o[4] = 0.f; o[5] = 0.f; o[6] = 0.f; o[7] = 0.f;
        o[8] = 0.f; o[9] = 0.f; o[10] = 0.f; o[11] = 0.f;
    }
    o[15] = (float)n;

    wf[(size_t)C * 1 + c] = (float)cx;
    wf[(size_t)C * 2 + c] = (float)cy;
    wf[(size_t)C * 3 + c] = (float)cz;
    wf[(size_t)C * 4 + c] = (float)v[0];
    wf[(size_t)C * 5 + c] = (float)v[1];
    wf[(size_t)C * 6 + c] = (float)v[2];
    wf[(size_t)C * 7 + c] = (float)dirwt;
}

__global__ void k3_sc(const float* __restrict__ data,
                      const int* __restrict__ cid,
                      float* __restrict__ wf,
                      int n_vox, int C) {
    const float* cenx = wf + (size_t)C * 1;
    const float* ceny = wf + (size_t)C * 2;
    const float* cenz = wf + (size_t)C * 3;
    const float* v0x  = wf + (size_t)C * 4;
    const float* v0y  = wf + (size_t)C * 5;
    const float* v0z  = wf + (size_t)C * 6;
    float* sc = wf;
    int stride = gridDim.x * blockDim.x;
    for (int i = blockIdx.x * blockDim.x + threadIdx.x; i < n_vox; i += stride) {
        int c = cid[i];
        const float* row = data + (size_t)i * 6;
        float x = row[1] - cenx[c];
        float y = row[2] - ceny[c];
        float z = row[3] - cenz[c];
        float vx = v0x[c], vy = v0y[c], vz = v0z[c];
        float x0 = x * vx + y * vy + z * vz;
        float px = x - x0 * vx;
        float py = y - x0 * vy;
        float pz = z - x0 * vz;
        atomicAdd(&sc[c], x0 * sqrtf(px * px + py * py + pz * pz));
    }
}

__global__ void k4_final(const unsigned long long* __restrict__ acc,
                         const float* __restrict__ wf,
                         float* __restrict__ out, int C) {
    int c = blockIdx.x * blockDim.x + threadIdx.x;
    if (c >= C) return;
    int n = (int)(acc[(size_t)c * 5 + 4] >> 32);
    float scv = wf[c];
    float vx  = wf[(size_t)C * 4 + c];
    float vy  = wf[(size_t)C * 5 + c];
    float vz  = wf[(size_t)C * 6 + c];
    float dir = wf[(size_t)C * 7 + c];
    float sgn = (scv < 0.0f) ? -1.0f : 1.0f;
    float m = (n >= 2) ? sgn * dir : 0.0f;
    float* o = out + (size_t)c * 16;
    o[12] = vx * m;
    o[13] = vy * m;
    o[14] = vz * m;
}

// ============================ launch =======================================
extern "C" void kernel_launch(void* const* d_in, const int* in_sizes, int n_in,
                              void* d_out, int out_size, void* d_ws, size_t ws_size,
                              hipStream_t stream) {
    const float* data = (const float*)d_in[0];
    const int*   cid  = (const int*)d_in[1];
    float* out = (float*)d_out;

    int n_vox = in_sizes[1];
    int C     = out_size / 16;

    int nbuckets = (C + NB_CL - 1) / NB_CL;
    long long expected = (C > 0) ? (long long)n_vox * NB_CL / C : 0;
    size_t gcnt_bytes = ((size_t)nbuckets * 4 + 255) & ~(size_t)255;
    size_t bbuf_bytes = (size_t)nbuckets * CAP2 * 16;
    size_t need = gcnt_bytes + bbuf_bytes + (size_t)nbuckets * CAP2;

    if (C > 0 && nbuckets <= NB_MAX && expected <= (CAP2 * 7) / 8 && ws_size >= need) {
        unsigned int* gcnt = (unsigned int*)d_ws;
        float4* bbuf = (float4*)((char*)d_ws + gcnt_bytes);
        unsigned char* lcb = (unsigned char*)((char*)d_ws + gcnt_bytes + bbuf_bytes);
        hipMemsetAsync(d_ws, 0, gcnt_bytes, stream);
        p1_bucket<<<512, P1_BLOCK, 0, stream>>>(data, cid, gcnt, bbuf, lcb, n_vox, nbuckets);
        p2_features<<<nbuckets, 512, 0, stream>>>(gcnt, bbuf, lcb, out, C);
    } else {
        unsigned long long* acc = (unsigned long long*)d_ws;
        float* wf = (float*)((char*)d_ws + (size_t)C * 40);
        hipMemsetAsync(d_ws, 0, (size_t)C * 44, stream);
        const int vox_blocks = 4096;
        const int cl_blocks  = (C + 255) / 256;
        k1_accum<<<vox_blocks, 256, 0, stream>>>(data, cid, acc, n_vox);
        k2_cluster<<<cl_blocks, 256, 0, stream>>>(acc, wf, out, C);
        k3_sc<<<vox_blocks, 256, 0, stream>>>(data, cid, wf, n_vox, C);
        k4_final<<<cl_blocks, 256, 0, stream>>>(acc, wf, out, C);
    }
}

// Round 10
// 150.604 us; speedup vs baseline: 1.1903x; 1.1903x over previous
//
#include <hip/hip_runtime.h>
#include <math.h>

// ---------------------------------------------------------------------------
// ClustGeoNodeEncoder via two-level bucket decomposition.
//
// Measured walls: global atomics ~16-23 G ops/s (r2-r4); LDS-atomic moments at
// low parallelism serialize (r5); redundant per-wave f64 eigen VALU-heavy (r6);
// bucket-splitting kills gather line locality (r7); 384KB windows + double
// gather thrash L2 (r8); 64-cl buckets fragment p1 scatter writes, and byte-
// array scatter is catastrophic (r9: 185MB WRITE for 68MB payload).
// Design (r10):
//   p1_bucket   : bucket = cid>>6. 8192-pt rounds (runs ~10.5 pts = ~3 full
//                 lines); cid low bits ride in .w (NO byte array); LDS
//                 ds_add_rtn ranks + per-round global alloc atomics (~380K).
//   p2_features : 1 block (1024 thr) per bucket; bucket (96KB) STAGED IN LDS
//                 via one coalesced stream (hist built in same pass), index
//                 counting-sort in LDS, moments/eigen/sc all from LDS.
//                 Zero HBM gathers.
// Fallback (small ws): round-2 packed u64 fixed-point pipeline.
// ---------------------------------------------------------------------------

#define NB_CL   64         // clusters per bucket
#define CAP2    6144       // per-bucket point capacity (mean 5120, +14 sigma)
#define NB_MAX  1024       // max buckets supported by p1's LDS histogram

// ========================= shared: 3x3 symmetric eigen =====================
__device__ inline void eig3_sym(double a00, double a01, double a02,
                                double a11, double a12, double a22,
                                double& w0, double& w1, double& w2,
                                double v[3]) {
    double p1 = a01 * a01 + a02 * a02 + a12 * a12;
    double q  = (a00 + a11 + a22) / 3.0;
    double d0 = a00 - q, d1 = a11 - q, d2 = a22 - q;
    double p2 = d0 * d0 + d1 * d1 + d2 * d2 + 2.0 * p1;
    double p  = sqrt(p2 / 6.0);
    if (p < 1e-300) {
        w0 = w1 = w2 = q;
        v[0] = 0.0; v[1] = 0.0; v[2] = 1.0;
        return;
    }
    double ip = 1.0 / p;
    double b00 = d0 * ip, b11 = d1 * ip, b22 = d2 * ip;
    double b01 = a01 * ip, b02 = a02 * ip, b12 = a12 * ip;
    double detB = b00 * (b11 * b22 - b12 * b12)
                - b01 * (b01 * b22 - b12 * b02)
                + b02 * (b01 * b12 - b11 * b02);
    double r = detB * 0.5;
    r = fmin(1.0, fmax(-1.0, r));
    double phi = acos(r) / 3.0;
    w2 = q + 2.0 * p * cos(phi);
    w0 = q + 2.0 * p * cos(phi + 2.0943951023931953);  // +2*pi/3
    w1 = 3.0 * q - w2 - w0;

    double r0x = a00 - w2, r0y = a01,       r0z = a02;
    double r1x = a01,      r1y = a11 - w2,  r1z = a12;
    double r2x = a02,      r2y = a12,       r2z = a22 - w2;

    double c0x = r0y * r1z - r0z * r1y;
    double c0y = r0z * r1x - r0x * r1z;
    double c0z = r0x * r1y - r0y * r1x;
    double n0  = c0x * c0x + c0y * c0y + c0z * c0z;

    double c1x = r0y * r2z - r0z * r2y;
    double c1y = r0z * r2x - r0x * r2z;
    double c1z = r0x * r2y - r0y * r2x;
    double n1  = c1x * c1x + c1y * c1y + c1z * c1z;

    double c2x = r1y * r2z - r1z * r2y;
    double c2y = r1z * r2x - r1x * r2z;
    double c2z = r1x * r2y - r1y * r2x;
    double n2  = c2x * c2x + c2y * c2y + c2z * c2z;

    double vx, vy, vz, nn;
    if (n0 >= n1 && n0 >= n2) { vx = c0x; vy = c0y; vz = c0z; nn = n0; }
    else if (n1 >= n2)        { vx = c1x; vy = c1y; vz = c1z; nn = n1; }
    else                      { vx = c2x; vy = c2y; vz = c2z; nn = n2; }
    if (nn < 1e-300) {
        v[0] = 0.0; v[1] = 0.0; v[2] = 1.0;
        return;
    }
    double inv = rsqrt(nn);
    v[0] = vx * inv; v[1] = vy * inv; v[2] = vz * inv;
}

// ============================ primary path =================================
#define P1_BLOCK 1024
#define P1_ITEMS 8     // voxels per thread per round -> 8192 per block-round

__global__ void p1_bucket(const float* __restrict__ data,
                          const int* __restrict__ cid,
                          unsigned int* __restrict__ gcnt,     // [nbuckets]
                          float4* __restrict__ bbuf,           // [nb*CAP2]
                          int n_vox, int nbuckets) {
    __shared__ unsigned int hist[NB_MAX];
    __shared__ unsigned int base[NB_MAX];
    const int tid = threadIdx.x;
    const int per_round = P1_BLOCK * P1_ITEMS;
    const int total_rounds = (n_vox + per_round - 1) / per_round;

    for (int r = blockIdx.x; r < total_rounds; r += gridDim.x) {
        const int start = r * per_round;
        for (int j = tid; j < nbuckets; j += P1_BLOCK) hist[j] = 0;
        __syncthreads();

        int   bk[P1_ITEMS];
        int   cd[P1_ITEMS];
        float px[P1_ITEMS], py[P1_ITEMS], pz[P1_ITEMS];
        unsigned int rk[P1_ITEMS];
#pragma unroll
        for (int k = 0; k < P1_ITEMS; ++k) {
            int i = start + tid + k * P1_BLOCK;   // coalesced lane pattern
            if (i < n_vox) {
                int c = cid[i];
                cd[k] = c & (NB_CL - 1);
                bk[k] = c >> 6;
                const float* row = data + (size_t)i * 6;
                px[k] = row[1]; py[k] = row[2]; pz[k] = row[3];
                rk[k] = atomicAdd(&hist[bk[k]], 1u);   // local rank
            } else {
                bk[k] = -1;
            }
        }
        __syncthreads();
        for (int j = tid; j < nbuckets; j += P1_BLOCK) {
            unsigned int h = hist[j];
            base[j] = h ? atomicAdd(&gcnt[j], h) : 0u;
        }
        __syncthreads();
#pragma unroll
        for (int k = 0; k < P1_ITEMS; ++k) {
            if (bk[k] >= 0) {
                unsigned int pos = base[bk[k]] + rk[k];
                if (pos < (unsigned int)CAP2) {
                    bbuf[(size_t)bk[k] * CAP2 + pos] =
                        make_float4(px[k], py[k], pz[k], __int_as_float(cd[k]));
                }
            }
        }
        __syncthreads();
    }
}

__global__ __launch_bounds__(1024) void p2_features(
        const unsigned int* __restrict__ gcnt,
        const float4* __restrict__ bbuf,
        float* __restrict__ out, int C) {
    __shared__ float4 sdata[CAP2];              // 96 KB — whole bucket in LDS
    __shared__ unsigned short sidx[CAP2];       // 12 KB
    __shared__ unsigned int hist[NB_CL];
    __shared__ unsigned int basex[NB_CL];
    __shared__ unsigned int hist2[NB_CL];
    __shared__ float mom[9][NB_CL];
    __shared__ float cenl[3][NB_CL], vvl[3][NB_CL], dwl[NB_CL];

    const int b   = blockIdx.x;
    const int tid = threadIdx.x;
    const int bcnt = min((int)gcnt[b], CAP2);
    const float4* src = bbuf + (size_t)b * CAP2;

    if (tid < NB_CL) { hist[tid] = 0; hist2[tid] = 0; }
    __syncthreads();

    // ---- stage bucket -> LDS (coalesced) + histogram in the same pass ----
    for (int i = tid; i < bcnt; i += 1024) {
        float4 p = src[i];
        sdata[i] = p;
        atomicAdd(&hist[__float_as_int(p.w) & (NB_CL - 1)], 1u);
    }
    __syncthreads();

    // ---- exclusive scan over 64 entries (wave 0 shfl scan) ----
    if (tid < NB_CL) {
        unsigned int h = hist[tid];
        unsigned int inc = h;
#pragma unroll
        for (int off = 1; off < NB_CL; off <<= 1) {
            unsigned int t = __shfl_up(inc, off);
            if (tid >= off) inc += t;
        }
        basex[tid] = inc - h;
    }
    __syncthreads();

    // ---- counting-sort indices (all LDS) ----
    for (int i = tid; i < bcnt; i += 1024) {
        int c = __float_as_int(sdata[i].w) & (NB_CL - 1);
        unsigned int rk = atomicAdd(&hist2[c], 1u);
        sidx[basex[c] + rk] = (unsigned short)i;
    }
    __syncthreads();

    const int w    = tid >> 6;     // 0..15
    const int lane = tid & 63;

    // ---- moments: 16 waves x 4 clusters, reads from LDS ----
#pragma unroll 1
    for (int jj = 0; jj < 4; ++jj) {
        const int lc = (w << 2) | jj;
        const int n  = (int)hist[lc];
        const unsigned int nb = basex[lc];
        float s0 = 0.f, s1 = 0.f, s2 = 0.f, s3 = 0.f, s4 = 0.f;
        float s5 = 0.f, s6 = 0.f, s7 = 0.f, s8 = 0.f;
        for (int j = lane; j < n; j += 64) {
            float4 p = sdata[sidx[nb + j]];
            s0 += p.x;       s1 += p.y;       s2 += p.z;
            s3 += p.x * p.x; s4 += p.x * p.y; s5 += p.x * p.z;
            s6 += p.y * p.y; s7 += p.y * p.z; s8 += p.z * p.z;
        }
#pragma unroll
        for (int d = 32; d > 0; d >>= 1) {
            s0 += __shfl_xor(s0, d); s1 += __shfl_xor(s1, d); s2 += __shfl_xor(s2, d);
            s3 += __shfl_xor(s3, d); s4 += __shfl_xor(s4, d); s5 += __shfl_xor(s5, d);
            s6 += __shfl_xor(s6, d); s7 += __shfl_xor(s7, d); s8 += __shfl_xor(s8, d);
        }
        if (lane == 0) {
            mom[0][lc] = s0; mom[1][lc] = s1; mom[2][lc] = s2;
            mom[3][lc] = s3; mom[4][lc] = s4; mom[5][lc] = s5;
            mom[6][lc] = s6; mom[7][lc] = s7; mom[8][lc] = s8;
        }
    }
    __syncthreads();

    // ---- lane-per-cluster f64 eigen (64 lanes) ----
    if (tid < NB_CL) {
        const int t  = tid;
        const int cl = b * NB_CL + t;
        if (cl < C) {
            const int n = (int)hist[t];
            double dn = (double)n;
            double nd = (double)max(n, 1);
            double cx = (double)mom[0][t] / nd;
            double cy = (double)mom[1][t] / nd;
            double cz = (double)mom[2][t] / nd;

            double axx = (double)mom[3][t] - dn * cx * cx;
            double axy = (double)mom[4][t] - dn * cx * cy;
            double axz = (double)mom[5][t] - dn * cx * cz;
            double ayy = (double)mom[6][t] - dn * cy * cy;
            double ayz = (double)mom[7][t] - dn * cy * cz;
            double azz = (double)mom[8][t] - dn * cz * cz;

            double w0, w1, w2, v[3];
            eig3_sym(axx, axy, axz, ayy, ayz, azz, w0, w1, w2, v);

            double safe_w2 = (w2 > 0.0) ? w2 : 1.0;
            double isw = 1.0 / safe_w2;
            bool multi = (n >= 2);

            float fcx = (float)cx, fcy = (float)cy, fcz = (float)cz;
            float b3  = multi ? (float)(axx * isw) : 0.0f;
            float b4  = multi ? (float)(axy * isw) : 0.0f;
            float b5  = multi ? (float)(axz * isw) : 0.0f;
            float b7  = multi ? (float)(ayy * isw) : 0.0f;
            float b8  = multi ? (float)(ayz * isw) : 0.0f;
            float b11 = multi ? (float)(azz * isw) : 0.0f;

            float4* o = (float4*)(out + (size_t)cl * 16);
            o[0] = make_float4(fcx, fcy, fcz, b3);
            o[1] = make_float4(b4, b5, b4, b7);
            o[2] = make_float4(b8, b5, b8, b11);

            cenl[0][t] = fcx; cenl[1][t] = fcy; cenl[2][t] = fcz;
            vvl[0][t] = (float)v[0]; vvl[1][t] = (float)v[1]; vvl[2][t] = (float)v[2];
            dwl[t] = (float)(1.0 - w1 / safe_w2);
        }
    }
    __syncthreads();

    // ---- sc pass from LDS -> final v0 ----
#pragma unroll 1
    for (int jj = 0; jj < 4; ++jj) {
        const int lc = (w << 2) | jj;
        const int cl = b * NB_CL + lc;
        if (cl >= C) continue;                  // wave-uniform
        const int n = (int)hist[lc];
        const unsigned int nb = basex[lc];
        const float fcx = cenl[0][lc], fcy = cenl[1][lc], fcz = cenl[2][lc];
        const float vx = vvl[0][lc], vy = vvl[1][lc], vz = vvl[2][lc];
        float sc = 0.0f;
        for (int j = lane; j < n; j += 64) {
            float4 p = sdata[sidx[nb + j]];
            float x = p.x - fcx, y = p.y - fcy, z = p.z - fcz;
            float x0 = x * vx + y * vy + z * vz;
            float qx = x - x0 * vx, qy = y - x0 * vy, qz = z - x0 * vz;
            sc += x0 * sqrtf(qx * qx + qy * qy + qz * qz);
        }
#pragma unroll
        for (int d = 32; d > 0; d >>= 1) sc += __shfl_xor(sc, d);

        if (lane == 0) {
            float sgn = (sc < 0.0f) ? -1.0f : 1.0f;
            float m = (n >= 2) ? sgn * dwl[lc] : 0.0f;
            ((float4*)(out + (size_t)cl * 16))[3] =
                make_float4(vx * m, vy * m, vz * m, (float)n);
        }
    }
}

// ============================ fallback path (round-2) ======================
#define FXP_SCALE 131072.0f
#define FXP_BIAS  4194304
#define FXP_INV   (1.0 / 131072.0)

__device__ __forceinline__ unsigned int fxp_enc(float v) {
    return (unsigned int)(__float2int_rn(v * FXP_SCALE) + FXP_BIAS);
}
__device__ __forceinline__ double fxp_dec(unsigned int s, int n) {
    return (double)((long long)s - (long long)n * FXP_BIAS) * FXP_INV;
}

__global__ void k1_accum(const float* __restrict__ data,
                         const int* __restrict__ cid,
                         unsigned long long* __restrict__ acc,
                         int n_vox) {
    int stride = gridDim.x * blockDim.x;
    for (int i = blockIdx.x * blockDim.x + threadIdx.x; i < n_vox; i += stride) {
        int c = cid[i];
        const float* row = data + (size_t)i * 6;
        float x = row[1], y = row[2], z = row[3];
        unsigned long long* a = acc + (size_t)c * 5;
        unsigned long long p0 = ((unsigned long long)fxp_enc(y)     << 32) | fxp_enc(x);
        unsigned long long p1 = ((unsigned long long)fxp_enc(x * x) << 32) | fxp_enc(z);
        unsigned long long p2 = ((unsigned long long)fxp_enc(x * z) << 32) | fxp_enc(x * y);
        unsigned long long p3 = ((unsigned long long)fxp_enc(y * z) << 32) | fxp_enc(y * y);
        unsigned long long p4 = (1ULL << 32)                               | fxp_enc(z * z);
        atomicAdd(&a[0], p0);
        atomicAdd(&a[1], p1);
        atomicAdd(&a[2], p2);
        atomicAdd(&a[3], p3);
        atomicAdd(&a[4], p4);
    }
}

__global__ void k2_cluster(const unsigned long long* __restrict__ acc,
                           float* __restrict__ wf,
                           float* __restrict__ out, int C) {
    int c = blockIdx.x * blockDim.x + threadIdx.x;
    if (c >= C) return;
    const unsigned long long* a = acc + (size_t)c * 5;
    unsigned long long s0 = a[0], s1 = a[1], s2 = a[2], s3 = a[3], s4 = a[4];
    int n = (int)(s4 >> 32);

    double sx  = fxp_dec((unsigned int)s0,         n);
    double sy  = fxp_dec((unsigned int)(s0 >> 32), n);
    double sz  = fxp_dec((unsigned int)s1,         n);
    double sxx = fxp_dec((unsigned int)(s1 >> 32), n);
    double sxy = fxp_dec((unsigned int)s2,         n);
    double sxz = fxp_dec((unsigned int)(s2 >> 32), n);
    double syy = fxp_dec((unsigned int)s3,         n);
    double syz = fxp_dec((unsigned int)(s3 >> 32), n);
    double szz = fxp_dec((unsigned int)s4,         n);

    double nd = (double)max(n, 1);
    double cx = sx / nd, cy = sy / nd, cz = sz / nd;
    double dn = (double)n;
    double axx = sxx - dn * cx * cx;
    double axy = sxy - dn * cx * cy;
    double axz = sxz - dn * cx * cz;
    double ayy = syy - dn * cy * cy;
    double ayz = syz - dn * cy * cz;
    double azz = szz - dn * cz * cz;

    double w0, w1, w2, v[3];
    eig3_sym(axx, axy, axz, ayy, ayz, azz, w0, w1, w2, v);

    double safe_w2 = (w2 > 0.0) ? w2 : 1.0;
    double dirwt   = 1.0 - w1 / safe_w2;
    double isw     = 1.0 / safe_w2;
    bool multi = (n >= 2);

    float* o = out + (size_t)c * 16;
    o[0] = (float)cx; o[1] = (float)cy; o[2] = (float)cz;
    if (multi) {
        o[3]  = (float)(axx * isw); o[4]  = (float)(axy * isw); o[5]  = (float)(axz * isw);
        o[6]  = (float)(axy * isw); o[7]  = (float)(ayy * isw); o[8]  = (float)(ayz * isw);
        o[9]  = (float)(axz * isw); o[10] = (float)(ayz * isw); o[11] = (float)(azz * isw);
    } else {
        o[3] = 0.f; o[4] = 0.f; o[5] = 0.f; o[6] = 0.f; o[7] = 0.f;
        o[8] = 0.f; o[9] = 0.f; o[10] = 0.f; o[11] = 0.f;
    }
    o[15] = (float)n;

    wf[(size_t)C * 1 + c] = (float)cx;
    wf[(size_t)C * 2 + c] = (float)cy;
    wf[(size_t)C * 3 + c] = (float)cz;
    wf[(size_t)C * 4 + c] = (float)v[0];
    wf[(size_t)C * 5 + c] = (float)v[1];
    wf[(size_t)C * 6 + c] = (float)v[2];
    wf[(size_t)C * 7 + c] = (float)dirwt;
}

__global__ void k3_sc(const float* __restrict__ data,
                      const int* __restrict__ cid,
                      float* __restrict__ wf,
                      int n_vox, int C) {
    const float* cenx = wf + (size_t)C * 1;
    const float* ceny = wf + (size_t)C * 2;
    const float* cenz = wf + (size_t)C * 3;
    const float* v0x  = wf + (size_t)C * 4;
    const float* v0y  = wf + (size_t)C * 5;
    const float* v0z  = wf + (size_t)C * 6;
    float* sc = wf;
    int stride = gridDim.x * blockDim.x;
    for (int i = blockIdx.x * blockDim.x + threadIdx.x; i < n_vox; i += stride) {
        int c = cid[i];
        const float* row = data + (size_t)i * 6;
        float x = row[1] - cenx[c];
        float y = row[2] - ceny[c];
        float z = row[3] - cenz[c];
        float vx = v0x[c], vy = v0y[c], vz = v0z[c];
        float x0 = x * vx + y * vy + z * vz;
        float px = x - x0 * vx;
        float py = y - x0 * vy;
        float pz = z - x0 * vz;
        atomicAdd(&sc[c], x0 * sqrtf(px * px + py * py + pz * pz));
    }
}

__global__ void k4_final(const unsigned long long* __restrict__ acc,
                         const float* __restrict__ wf,
                         float* __restrict__ out, int C) {
    int c = blockIdx.x * blockDim.x + threadIdx.x;
    if (c >= C) return;
    int n = (int)(acc[(size_t)c * 5 + 4] >> 32);
    float scv = wf[c];
    float vx  = wf[(size_t)C * 4 + c];
    float vy  = wf[(size_t)C * 5 + c];
    float vz  = wf[(size_t)C * 6 + c];
    float dir = wf[(size_t)C * 7 + c];
    float sgn = (scv < 0.0f) ? -1.0f : 1.0f;
    float m = (n >= 2) ? sgn * dir : 0.0f;
    float* o = out + (size_t)c * 16;
    o[12] = vx * m;
    o[13] = vy * m;
    o[14] = vz * m;
}

// ============================ launch =======================================
extern "C" void kernel_launch(void* const* d_in, const int* in_sizes, int n_in,
                              void* d_out, int out_size, void* d_ws, size_t ws_size,
                              hipStream_t stream) {
    const float* data = (const float*)d_in[0];
    const int*   cid  = (const int*)d_in[1];
    float* out = (float*)d_out;

    int n_vox = in_sizes[1];
    int C     = out_size / 16;

    int nbuckets = (C + NB_CL - 1) / NB_CL;
    long long expected = (C > 0) ? (long long)n_vox * NB_CL / C : 0;
    size_t gcnt_bytes = ((size_t)nbuckets * 4 + 255) & ~(size_t)255;
    size_t bbuf_bytes = (size_t)nbuckets * CAP2 * 16;
    size_t need = gcnt_bytes + bbuf_bytes;

    if (C > 0 && nbuckets <= NB_MAX && expected <= (CAP2 * 7) / 8 && ws_size >= need) {
        unsigned int* gcnt = (unsigned int*)d_ws;
        float4* bbuf = (float4*)((char*)d_ws + gcnt_bytes);
        hipMemsetAsync(d_ws, 0, gcnt_bytes, stream);
        int total_rounds = (n_vox + P1_BLOCK * P1_ITEMS - 1) / (P1_BLOCK * P1_ITEMS);
        int p1_blocks = total_rounds < 1024 ? total_rounds : 1024;
        if (p1_blocks < 1) p1_blocks = 1;
        p1_bucket<<<p1_blocks, P1_BLOCK, 0, stream>>>(data, cid, gcnt, bbuf, n_vox, nbuckets);
        p2_features<<<nbuckets, 1024, 0, stream>>>(gcnt, bbuf, out, C);
    } else {
        unsigned long long* acc = (unsigned long long*)d_ws;
        float* wf = (float*)((char*)d_ws + (size_t)C * 40);
        hipMemsetAsync(d_ws, 0, (size_t)C * 44, stream);
        const int vox_blocks = 4096;
        const int cl_blocks  = (C + 255) / 256;
        k1_accum<<<vox_blocks, 256, 0, stream>>>(data, cid, acc, n_vox);
        k2_cluster<<<cl_blocks, 256, 0, stream>>>(acc, wf, out, C);
        k3_sc<<<vox_blocks, 256, 0, stream>>>(data, cid, wf, n_vox, C);
        k4_final<<<cl_blocks, 256, 0, stream>>>(acc, wf, out, C);
    }
}

// Round 11
// 147.860 us; speedup vs baseline: 1.2124x; 1.0186x over previous
//
#include <hip/hip_runtime.h>
#include <math.h>

// ---------------------------------------------------------------------------
// ClustGeoNodeEncoder via two-level bucket decomposition.
//
// Measured walls: global atomics ~16-23 G ops/s (r2-r4); LDS-atomic moments at
// low parallelism serialize (r5); redundant f64 eigen VALU-heavy (r6); bucket
// splitting kills gather locality (r7); L2 thrash at 384KB windows (r8); byte-
// scatter write amplification (r9); 113KB-LDS staging + random 16B LDS gathers
// + 1 block/CU = conflict/latency bound p2 (r10: 3.95M conflict cy, occ 33%).
// Design (r11):
//   p1_bucket   : unchanged from r10 (90 us; scatter write amp is the known
//                 remaining cost, to be addressed separately).
//   p2_features : 1 block per bucket, TWO passes over L3-hot bbuf:
//                 A: histogram of .w only; 64-entry scan.
//                 B: place x,y,z into SORTED per-cluster LDS arrays sx/sy/sz.
//                 Moments + sc then read LDS LINEARLY (conflict-free).
//                 77 KB LDS -> 2 blocks/CU (eigen + latency overlap).
// Fallback (small ws): round-2 packed u64 fixed-point pipeline.
// ---------------------------------------------------------------------------

#define NB_CL   64         // clusters per bucket
#define CAP2    6144       // per-bucket point capacity (mean 5120, +14 sigma)
#define NB_MAX  1024       // max buckets supported by p1's LDS histogram

// ========================= shared: 3x3 symmetric eigen =====================
__device__ inline void eig3_sym(double a00, double a01, double a02,
                                double a11, double a12, double a22,
                                double& w0, double& w1, double& w2,
                                double v[3]) {
    double p1 = a01 * a01 + a02 * a02 + a12 * a12;
    double q  = (a00 + a11 + a22) / 3.0;
    double d0 = a00 - q, d1 = a11 - q, d2 = a22 - q;
    double p2 = d0 * d0 + d1 * d1 + d2 * d2 + 2.0 * p1;
    double p  = sqrt(p2 / 6.0);
    if (p < 1e-300) {
        w0 = w1 = w2 = q;
        v[0] = 0.0; v[1] = 0.0; v[2] = 1.0;
        return;
    }
    double ip = 1.0 / p;
    double b00 = d0 * ip, b11 = d1 * ip, b22 = d2 * ip;
    double b01 = a01 * ip, b02 = a02 * ip, b12 = a12 * ip;
    double detB = b00 * (b11 * b22 - b12 * b12)
                - b01 * (b01 * b22 - b12 * b02)
                + b02 * (b01 * b12 - b11 * b02);
    double r = detB * 0.5;
    r = fmin(1.0, fmax(-1.0, r));
    double phi = acos(r) / 3.0;
    w2 = q + 2.0 * p * cos(phi);
    w0 = q + 2.0 * p * cos(phi + 2.0943951023931953);  // +2*pi/3
    w1 = 3.0 * q - w2 - w0;

    double r0x = a00 - w2, r0y = a01,       r0z = a02;
    double r1x = a01,      r1y = a11 - w2,  r1z = a12;
    double r2x = a02,      r2y = a12,       r2z = a22 - w2;

    double c0x = r0y * r1z - r0z * r1y;
    double c0y = r0z * r1x - r0x * r1z;
    double c0z = r0x * r1y - r0y * r1x;
    double n0  = c0x * c0x + c0y * c0y + c0z * c0z;

    double c1x = r0y * r2z - r0z * r2y;
    double c1y = r0z * r2x - r0x * r2z;
    double c1z = r0x * r2y - r0y * r2x;
    double n1  = c1x * c1x + c1y * c1y + c1z * c1z;

    double c2x = r1y * r2z - r1z * r2y;
    double c2y = r1z * r2x - r1x * r2z;
    double c2z = r1x * r2y - r1y * r2x;
    double n2  = c2x * c2x + c2y * c2y + c2z * c2z;

    double vx, vy, vz, nn;
    if (n0 >= n1 && n0 >= n2) { vx = c0x; vy = c0y; vz = c0z; nn = n0; }
    else if (n1 >= n2)        { vx = c1x; vy = c1y; vz = c1z; nn = n1; }
    else                      { vx = c2x; vy = c2y; vz = c2z; nn = n2; }
    if (nn < 1e-300) {
        v[0] = 0.0; v[1] = 0.0; v[2] = 1.0;
        return;
    }
    double inv = rsqrt(nn);
    v[0] = vx * inv; v[1] = vy * inv; v[2] = vz * inv;
}

// ============================ primary path =================================
#define P1_BLOCK 1024
#define P1_ITEMS 8     // voxels per thread per round -> 8192 per block-round

__global__ void p1_bucket(const float* __restrict__ data,
                          const int* __restrict__ cid,
                          unsigned int* __restrict__ gcnt,     // [nbuckets]
                          float4* __restrict__ bbuf,           // [nb*CAP2]
                          int n_vox, int nbuckets) {
    __shared__ unsigned int hist[NB_MAX];
    __shared__ unsigned int base[NB_MAX];
    const int tid = threadIdx.x;
    const int per_round = P1_BLOCK * P1_ITEMS;
    const int total_rounds = (n_vox + per_round - 1) / per_round;

    for (int r = blockIdx.x; r < total_rounds; r += gridDim.x) {
        const int start = r * per_round;
        for (int j = tid; j < nbuckets; j += P1_BLOCK) hist[j] = 0;
        __syncthreads();

        int   bk[P1_ITEMS];
        int   cd[P1_ITEMS];
        float px[P1_ITEMS], py[P1_ITEMS], pz[P1_ITEMS];
        unsigned int rk[P1_ITEMS];
#pragma unroll
        for (int k = 0; k < P1_ITEMS; ++k) {
            int i = start + tid + k * P1_BLOCK;   // coalesced lane pattern
            if (i < n_vox) {
                int c = cid[i];
                cd[k] = c & (NB_CL - 1);
                bk[k] = c >> 6;
                const float* row = data + (size_t)i * 6;
                px[k] = row[1]; py[k] = row[2]; pz[k] = row[3];
                rk[k] = atomicAdd(&hist[bk[k]], 1u);   // local rank
            } else {
                bk[k] = -1;
            }
        }
        __syncthreads();
        for (int j = tid; j < nbuckets; j += P1_BLOCK) {
            unsigned int h = hist[j];
            base[j] = h ? atomicAdd(&gcnt[j], h) : 0u;
        }
        __syncthreads();
#pragma unroll
        for (int k = 0; k < P1_ITEMS; ++k) {
            if (bk[k] >= 0) {
                unsigned int pos = base[bk[k]] + rk[k];
                if (pos < (unsigned int)CAP2) {
                    bbuf[(size_t)bk[k] * CAP2 + pos] =
                        make_float4(px[k], py[k], pz[k], __int_as_float(cd[k]));
                }
            }
        }
        __syncthreads();
    }
}

__global__ __launch_bounds__(1024) void p2_features(
        const unsigned int* __restrict__ gcnt,
        const float4* __restrict__ bbuf,
        float* __restrict__ out, int C) {
    __shared__ float sx[CAP2];                  // 24 KB  sorted x
    __shared__ float sy[CAP2];                  // 24 KB  sorted y
    __shared__ float sz[CAP2];                  // 24 KB  sorted z
    __shared__ unsigned int hist[NB_CL];
    __shared__ unsigned int basex[NB_CL];
    __shared__ unsigned int hist2[NB_CL];
    __shared__ float mom[9][NB_CL];
    __shared__ float cenl[3][NB_CL], vvl[3][NB_CL], dwl[NB_CL];

    const int b   = blockIdx.x;
    const int tid = threadIdx.x;
    const int bcnt = min((int)gcnt[b], CAP2);
    const float4* src = bbuf + (size_t)b * CAP2;

    if (tid < NB_CL) { hist[tid] = 0; hist2[tid] = 0; }
    __syncthreads();

    // ---- pass A: histogram of cluster tags (bbuf is L3-hot) ----
    for (int i = tid; i < bcnt; i += 1024) {
        float4 p = src[i];
        atomicAdd(&hist[__float_as_int(p.w) & (NB_CL - 1)], 1u);
    }
    __syncthreads();

    // ---- exclusive scan over 64 entries (wave 0 shfl scan) ----
    if (tid < NB_CL) {
        unsigned int h = hist[tid];
        unsigned int inc = h;
#pragma unroll
        for (int off = 1; off < NB_CL; off <<= 1) {
            unsigned int t = __shfl_up(inc, off);
            if (tid >= off) inc += t;
        }
        basex[tid] = inc - h;
    }
    __syncthreads();

    // ---- pass B: place x,y,z into sorted LDS arrays ----
    for (int i = tid; i < bcnt; i += 1024) {
        float4 p = src[i];
        int c = __float_as_int(p.w) & (NB_CL - 1);
        unsigned int rk = atomicAdd(&hist2[c], 1u);
        unsigned int pos = basex[c] + rk;
        sx[pos] = p.x; sy[pos] = p.y; sz[pos] = p.z;
    }
    __syncthreads();

    const int w    = tid >> 6;     // 0..15
    const int lane = tid & 63;

    // ---- moments: 16 waves x 4 clusters, LINEAR conflict-free LDS reads ----
#pragma unroll 1
    for (int jj = 0; jj < 4; ++jj) {
        const int lc = (w << 2) | jj;
        const int n  = (int)hist[lc];
        const unsigned int nb = basex[lc];
        float s0 = 0.f, s1 = 0.f, s2 = 0.f, s3 = 0.f, s4 = 0.f;
        float s5 = 0.f, s6 = 0.f, s7 = 0.f, s8 = 0.f;
        for (int j = lane; j < n; j += 64) {
            float x = sx[nb + j], y = sy[nb + j], z = sz[nb + j];
            s0 += x;     s1 += y;     s2 += z;
            s3 += x * x; s4 += x * y; s5 += x * z;
            s6 += y * y; s7 += y * z; s8 += z * z;
        }
#pragma unroll
        for (int d = 32; d > 0; d >>= 1) {
            s0 += __shfl_xor(s0, d); s1 += __shfl_xor(s1, d); s2 += __shfl_xor(s2, d);
            s3 += __shfl_xor(s3, d); s4 += __shfl_xor(s4, d); s5 += __shfl_xor(s5, d);
            s6 += __shfl_xor(s6, d); s7 += __shfl_xor(s7, d); s8 += __shfl_xor(s8, d);
        }
        if (lane == 0) {
            mom[0][lc] = s0; mom[1][lc] = s1; mom[2][lc] = s2;
            mom[3][lc] = s3; mom[4][lc] = s4; mom[5][lc] = s5;
            mom[6][lc] = s6; mom[7][lc] = s7; mom[8][lc] = s8;
        }
    }
    __syncthreads();

    // ---- lane-per-cluster f64 eigen (64 lanes; 2nd block/CU overlaps) ----
    if (tid < NB_CL) {
        const int t  = tid;
        const int cl = b * NB_CL + t;
        if (cl < C) {
            const int n = (int)hist[t];
            double dn = (double)n;
            double nd = (double)max(n, 1);
            double cx = (double)mom[0][t] / nd;
            double cy = (double)mom[1][t] / nd;
            double cz = (double)mom[2][t] / nd;

            double axx = (double)mom[3][t] - dn * cx * cx;
            double axy = (double)mom[4][t] - dn * cx * cy;
            double axz = (double)mom[5][t] - dn * cx * cz;
            double ayy = (double)mom[6][t] - dn * cy * cy;
            double ayz = (double)mom[7][t] - dn * cy * cz;
            double azz = (double)mom[8][t] - dn * cz * cz;

            double w0, w1, w2, v[3];
            eig3_sym(axx, axy, axz, ayy, ayz, azz, w0, w1, w2, v);

            double safe_w2 = (w2 > 0.0) ? w2 : 1.0;
            double isw = 1.0 / safe_w2;
            bool multi = (n >= 2);

            float fcx = (float)cx, fcy = (float)cy, fcz = (float)cz;
            float b3  = multi ? (float)(axx * isw) : 0.0f;
            float b4  = multi ? (float)(axy * isw) : 0.0f;
            float b5  = multi ? (float)(axz * isw) : 0.0f;
            float b7  = multi ? (float)(ayy * isw) : 0.0f;
            float b8  = multi ? (float)(ayz * isw) : 0.0f;
            float b11 = multi ? (float)(azz * isw) : 0.0f;

            float4* o = (float4*)(out + (size_t)cl * 16);
            o[0] = make_float4(fcx, fcy, fcz, b3);
            o[1] = make_float4(b4, b5, b4, b7);
            o[2] = make_float4(b8, b5, b8, b11);

            cenl[0][t] = fcx; cenl[1][t] = fcy; cenl[2][t] = fcz;
            vvl[0][t] = (float)v[0]; vvl[1][t] = (float)v[1]; vvl[2][t] = (float)v[2];
            dwl[t] = (float)(1.0 - w1 / safe_w2);
        }
    }
    __syncthreads();

    // ---- sc pass (linear LDS reads) -> final v0 ----
#pragma unroll 1
    for (int jj = 0; jj < 4; ++jj) {
        const int lc = (w << 2) | jj;
        const int cl = b * NB_CL + lc;
        if (cl >= C) continue;                  // wave-uniform
        const int n = (int)hist[lc];
        const unsigned int nb = basex[lc];
        const float fcx = cenl[0][lc], fcy = cenl[1][lc], fcz = cenl[2][lc];
        const float vx = vvl[0][lc], vy = vvl[1][lc], vz = vvl[2][lc];
        float sc = 0.0f;
        for (int j = lane; j < n; j += 64) {
            float x = sx[nb + j] - fcx, y = sy[nb + j] - fcy, z = sz[nb + j] - fcz;
            float x0 = x * vx + y * vy + z * vz;
            float qx = x - x0 * vx, qy = y - x0 * vy, qz = z - x0 * vz;
            sc += x0 * sqrtf(qx * qx + qy * qy + qz * qz);
        }
#pragma unroll
        for (int d = 32; d > 0; d >>= 1) sc += __shfl_xor(sc, d);

        if (lane == 0) {
            float sgn = (sc < 0.0f) ? -1.0f : 1.0f;
            float m = (n >= 2) ? sgn * dwl[lc] : 0.0f;
            ((float4*)(out + (size_t)cl * 16))[3] =
                make_float4(vx * m, vy * m, vz * m, (float)n);
        }
    }
}

// ============================ fallback path (round-2) ======================
#define FXP_SCALE 131072.0f
#define FXP_BIAS  4194304
#define FXP_INV   (1.0 / 131072.0)

__device__ __forceinline__ unsigned int fxp_enc(float v) {
    return (unsigned int)(__float2int_rn(v * FXP_SCALE) + FXP_BIAS);
}
__device__ __forceinline__ double fxp_dec(unsigned int s, int n) {
    return (double)((long long)s - (long long)n * FXP_BIAS) * FXP_INV;
}

__global__ void k1_accum(const float* __restrict__ data,
                         const int* __restrict__ cid,
                         unsigned long long* __restrict__ acc,
                         int n_vox) {
    int stride = gridDim.x * blockDim.x;
    for (int i = blockIdx.x * blockDim.x + threadIdx.x; i < n_vox; i += stride) {
        int c = cid[i];
        const float* row = data + (size_t)i * 6;
        float x = row[1], y = row[2], z = row[3];
        unsigned long long* a = acc + (size_t)c * 5;
        unsigned long long p0 = ((unsigned long long)fxp_enc(y)     << 32) | fxp_enc(x);
        unsigned long long p1 = ((unsigned long long)fxp_enc(x * x) << 32) | fxp_enc(z);
        unsigned long long p2 = ((unsigned long long)fxp_enc(x * z) << 32) | fxp_enc(x * y);
        unsigned long long p3 = ((unsigned long long)fxp_enc(y * z) << 32) | fxp_enc(y * y);
        unsigned long long p4 = (1ULL << 32)                               | fxp_enc(z * z);
        atomicAdd(&a[0], p0);
        atomicAdd(&a[1], p1);
        atomicAdd(&a[2], p2);
        atomicAdd(&a[3], p3);
        atomicAdd(&a[4], p4);
    }
}

__global__ void k2_cluster(const unsigned long long* __restrict__ acc,
                           float* __restrict__ wf,
                           float* __restrict__ out, int C) {
    int c = blockIdx.x * blockDim.x + threadIdx.x;
    if (c >= C) return;
    const unsigned long long* a = acc + (size_t)c * 5;
    unsigned long long s0 = a[0], s1 = a[1], s2 = a[2], s3 = a[3], s4 = a[4];
    int n = (int)(s4 >> 32);

    double sx  = fxp_dec((unsigned int)s0,         n);
    double sy  = fxp_dec((unsigned int)(s0 >> 32), n);
    double sz  = fxp_dec((unsigned int)s1,         n);
    double sxx = fxp_dec((unsigned int)(s1 >> 32), n);
    double sxy = fxp_dec((unsigned int)s2,         n);
    double sxz = fxp_dec((unsigned int)(s2 >> 32), n);
    double syy = fxp_dec((unsigned int)s3,         n);
    double syz = fxp_dec((unsigned int)(s3 >> 32), n);
    double szz = fxp_dec((unsigned int)s4,         n);

    double nd = (double)max(n, 1);
    double cx = sx / nd, cy = sy / nd, cz = sz / nd;
    double dn = (double)n;
    double axx = sxx - dn * cx * cx;
    double axy = sxy - dn * cx * cy;
    double axz = sxz - dn * cx * cz;
    double ayy = syy - dn * cy * cy;
    double ayz = syz - dn * cy * cz;
    double azz = szz - dn * cz * cz;

    double w0, w1, w2, v[3];
    eig3_sym(axx, axy, axz, ayy, ayz, azz, w0, w1, w2, v);

    double safe_w2 = (w2 > 0.0) ? w2 : 1.0;
    double dirwt   = 1.0 - w1 / safe_w2;
    double isw     = 1.0 / safe_w2;
    bool multi = (n >= 2);

    float* o = out + (size_t)c * 16;
    o[0] = (float)cx; o[1] = (float)cy; o[2] = (float)cz;
    if (multi) {
        o[3]  = (float)(axx * isw); o[4]  = (float)(axy * isw); o[5]  = (float)(axz * isw);
        o[6]  = (float)(axy * isw); o[7]  = (float)(ayy * isw); o[8]  = (float)(ayz * isw);
        o[9]  = (float)(axz * isw); o[10] = (float)(ayz * isw); o[11] = (float)(azz * isw);
    } else {
        o[3] = 0.f; o[4] = 0.f; o[5] = 0.f; o[6] = 0.f; o[7] = 0.f;
        o[8] = 0.f; o[9] = 0.f; o[10] = 0.f; o[11] = 0.f;
    }
    o[15] = (float)n;

    wf[(size_t)C * 1 + c] = (float)cx;
    wf[(size_t)C * 2 + c] = (float)cy;
    wf[(size_t)C * 3 + c] = (float)cz;
    wf[(size_t)C * 4 + c] = (float)v[0];
    wf[(size_t)C * 5 + c] = (float)v[1];
    wf[(size_t)C * 6 + c] = (float)v[2];
    wf[(size_t)C * 7 + c] = (float)dirwt;
}

__global__ void k3_sc(const float* __restrict__ data,
                      const int* __restrict__ cid,
                      float* __restrict__ wf,
                      int n_vox, int C) {
    const float* cenx = wf + (size_t)C * 1;
    const float* ceny = wf + (size_t)C * 2;
    const float* cenz = wf + (size_t)C * 3;
    const float* v0x  = wf + (size_t)C * 4;
    const float* v0y  = wf + (size_t)C * 5;
    const float* v0z  = wf + (size_t)C * 6;
    float* sc = wf;
    int stride = gridDim.x * blockDim.x;
    for (int i = blockIdx.x * blockDim.x + threadIdx.x; i < n_vox; i += stride) {
        int c = cid[i];
        const float* row = data + (size_t)i * 6;
        float x = row[1] - cenx[c];
        float y = row[2] - ceny[c];
        float z = row[3] - cenz[c];
        float vx = v0x[c], vy = v0y[c], vz = v0z[c];
        float x0 = x * vx + y * vy + z * vz;
        float px = x - x0 * vx;
        float py = y - x0 * vy;
        float pz = z - x0 * vz;
        atomicAdd(&sc[c], x0 * sqrtf(px * px + py * py + pz * pz));
    }
}

__global__ void k4_final(const unsigned long long* __restrict__ acc,
                         const float* __restrict__ wf,
                         float* __restrict__ out, int C) {
    int c = blockIdx.x * blockDim.x + threadIdx.x;
    if (c >= C) return;
    int n = (int)(acc[(size_t)c * 5 + 4] >> 32);
    float scv = wf[c];
    float vx  = wf[(size_t)C * 4 + c];
    float vy  = wf[(size_t)C * 5 + c];
    float vz  = wf[(size_t)C * 6 + c];
    float dir = wf[(size_t)C * 7 + c];
    float sgn = (scv < 0.0f) ? -1.0f : 1.0f;
    float m = (n >= 2) ? sgn * dir : 0.0f;
    float* o = out + (size_t)c * 16;
    o[12] = vx * m;
    o[13] = vy * m;
    o[14] = vz * m;
}

// ============================ launch =======================================
extern "C" void kernel_launch(void* const* d_in, const int* in_sizes, int n_in,
                              void* d_out, int out_size, void* d_ws, size_t ws_size,
                              hipStream_t stream) {
    const float* data = (const float*)d_in[0];
    const int*   cid  = (const int*)d_in[1];
    float* out = (float*)d_out;

    int n_vox = in_sizes[1];
    int C     = out_size / 16;

    int nbuckets = (C + NB_CL - 1) / NB_CL;
    long long expected = (C > 0) ? (long long)n_vox * NB_CL / C : 0;
    size_t gcnt_bytes = ((size_t)nbuckets * 4 + 255) & ~(size_t)255;
    size_t bbuf_bytes = (size_t)nbuckets * CAP2 * 16;
    size_t need = gcnt_bytes + bbuf_bytes;

    if (C > 0 && nbuckets <= NB_MAX && expected <= (CAP2 * 7) / 8 && ws_size >= need) {
        unsigned int* gcnt = (unsigned int*)d_ws;
        float4* bbuf = (float4*)((char*)d_ws + gcnt_bytes);
        hipMemsetAsync(d_ws, 0, gcnt_bytes, stream);
        int total_rounds = (n_vox + P1_BLOCK * P1_ITEMS - 1) / (P1_BLOCK * P1_ITEMS);
        int p1_blocks = total_rounds < 1024 ? total_rounds : 1024;
        if (p1_blocks < 1) p1_blocks = 1;
        p1_bucket<<<p1_blocks, P1_BLOCK, 0, stream>>>(data, cid, gcnt, bbuf, n_vox, nbuckets);
        p2_features<<<nbuckets, 1024, 0, stream>>>(gcnt, bbuf, out, C);
    } else {
        unsigned long long* acc = (unsigned long long*)d_ws;
        float* wf = (float*)((char*)d_ws + (size_t)C * 40);
        hipMemsetAsync(d_ws, 0, (size_t)C * 44, stream);
        const int vox_blocks = 4096;
        const int cl_blocks  = (C + 255) / 256;
        k1_accum<<<vox_blocks, 256, 0, stream>>>(data, cid, acc, n_vox);
        k2_cluster<<<cl_blocks, 256, 0, stream>>>(acc, wf, out, C);
        k3_sc<<<vox_blocks, 256, 0, stream>>>(data, cid, wf, n_vox, C);
        k4_final<<<cl_blocks, 256, 0, stream>>>(acc, wf, out, C);
    }
}

// Round 12
// 140.866 us; speedup vs baseline: 1.2726x; 1.0497x over previous
//
#include <hip/hip_runtime.h>
#include <math.h>

// ---------------------------------------------------------------------------
// ClustGeoNodeEncoder via two-level bucket decomposition.
//
// Measured walls: global atomics ~16-23 G ops/s (r2-r4); LDS-atomic moments at
// low parallelism serialize (r5); redundant f64 eigen VALU-heavy (r6); bucket
// splitting kills gather locality (r7); L2 thrash at 384KB windows (r8); byte-
// scatter write amplification (r9); random 16B LDS gathers conflict (r10);
// p2 streaming passes are L3-latency bound at 1 block/CU + serial eigen tail
// (r11: 85us, occ 34%, VALU 21%).
// Design (r12):
//   p1_bucket   : unchanged from r11 (~88 us; scatter write amp ~2.2x is the
//                 known remaining cost, separate experiment).
//   p2_features : 512-thr block per bucket (74.5KB LDS -> 2 blocks/CU).
//                 A: histogram of 4B tags, ILP x4 batched loads.
//                 B: sorted placement into LDS sx/sy/sz, ILP x4 batched.
//                 Tail BARRIER-FREE per wave: 8 clusters/wave, butterfly
//                 moments kept in lane-jj registers, 8 f64 eigens on lanes
//                 0-7, shfl broadcast, sc from linear LDS.
// Fallback (small ws): round-2 packed u64 fixed-point pipeline.
// ---------------------------------------------------------------------------

#define NB_CL   64         // clusters per bucket
#define CAP2    6144       // per-bucket point capacity (mean 5120, +14 sigma)
#define NB_MAX  1024       // max buckets supported by p1's LDS histogram

// ========================= shared: 3x3 symmetric eigen =====================
__device__ inline void eig3_sym(double a00, double a01, double a02,
                                double a11, double a12, double a22,
                                double& w0, double& w1, double& w2,
                                double v[3]) {
    double p1 = a01 * a01 + a02 * a02 + a12 * a12;
    double q  = (a00 + a11 + a22) / 3.0;
    double d0 = a00 - q, d1 = a11 - q, d2 = a22 - q;
    double p2 = d0 * d0 + d1 * d1 + d2 * d2 + 2.0 * p1;
    double p  = sqrt(p2 / 6.0);
    if (p < 1e-300) {
        w0 = w1 = w2 = q;
        v[0] = 0.0; v[1] = 0.0; v[2] = 1.0;
        return;
    }
    double ip = 1.0 / p;
    double b00 = d0 * ip, b11 = d1 * ip, b22 = d2 * ip;
    double b01 = a01 * ip, b02 = a02 * ip, b12 = a12 * ip;
    double detB = b00 * (b11 * b22 - b12 * b12)
                - b01 * (b01 * b22 - b12 * b02)
                + b02 * (b01 * b12 - b11 * b02);
    double r = detB * 0.5;
    r = fmin(1.0, fmax(-1.0, r));
    double phi = acos(r) / 3.0;
    w2 = q + 2.0 * p * cos(phi);
    w0 = q + 2.0 * p * cos(phi + 2.0943951023931953);  // +2*pi/3
    w1 = 3.0 * q - w2 - w0;

    double r0x = a00 - w2, r0y = a01,       r0z = a02;
    double r1x = a01,      r1y = a11 - w2,  r1z = a12;
    double r2x = a02,      r2y = a12,       r2z = a22 - w2;

    double c0x = r0y * r1z - r0z * r1y;
    double c0y = r0z * r1x - r0x * r1z;
    double c0z = r0x * r1y - r0y * r1x;
    double n0  = c0x * c0x + c0y * c0y + c0z * c0z;

    double c1x = r0y * r2z - r0z * r2y;
    double c1y = r0z * r2x - r0x * r2z;
    double c1z = r0x * r2y - r0y * r2x;
    double n1  = c1x * c1x + c1y * c1y + c1z * c1z;

    double c2x = r1y * r2z - r1z * r2y;
    double c2y = r1z * r2x - r1x * r2z;
    double c2z = r1x * r2y - r1y * r2x;
    double n2  = c2x * c2x + c2y * c2y + c2z * c2z;

    double vx, vy, vz, nn;
    if (n0 >= n1 && n0 >= n2) { vx = c0x; vy = c0y; vz = c0z; nn = n0; }
    else if (n1 >= n2)        { vx = c1x; vy = c1y; vz = c1z; nn = n1; }
    else                      { vx = c2x; vy = c2y; vz = c2z; nn = n2; }
    if (nn < 1e-300) {
        v[0] = 0.0; v[1] = 0.0; v[2] = 1.0;
        return;
    }
    double inv = rsqrt(nn);
    v[0] = vx * inv; v[1] = vy * inv; v[2] = vz * inv;
}

// ============================ primary path =================================
#define P1_BLOCK 1024
#define P1_ITEMS 8     // voxels per thread per round -> 8192 per block-round

__global__ void p1_bucket(const float* __restrict__ data,
                          const int* __restrict__ cid,
                          unsigned int* __restrict__ gcnt,     // [nbuckets]
                          float4* __restrict__ bbuf,           // [nb*CAP2]
                          int n_vox, int nbuckets) {
    __shared__ unsigned int hist[NB_MAX];
    __shared__ unsigned int base[NB_MAX];
    const int tid = threadIdx.x;
    const int per_round = P1_BLOCK * P1_ITEMS;
    const int total_rounds = (n_vox + per_round - 1) / per_round;

    for (int r = blockIdx.x; r < total_rounds; r += gridDim.x) {
        const int start = r * per_round;
        for (int j = tid; j < nbuckets; j += P1_BLOCK) hist[j] = 0;
        __syncthreads();

        int   bk[P1_ITEMS];
        int   cd[P1_ITEMS];
        float px[P1_ITEMS], py[P1_ITEMS], pz[P1_ITEMS];
        unsigned int rk[P1_ITEMS];
#pragma unroll
        for (int k = 0; k < P1_ITEMS; ++k) {
            int i = start + tid + k * P1_BLOCK;   // coalesced lane pattern
            if (i < n_vox) {
                int c = cid[i];
                cd[k] = c & (NB_CL - 1);
                bk[k] = c >> 6;
                const float* row = data + (size_t)i * 6;
                px[k] = row[1]; py[k] = row[2]; pz[k] = row[3];
                rk[k] = atomicAdd(&hist[bk[k]], 1u);   // local rank
            } else {
                bk[k] = -1;
            }
        }
        __syncthreads();
        for (int j = tid; j < nbuckets; j += P1_BLOCK) {
            unsigned int h = hist[j];
            base[j] = h ? atomicAdd(&gcnt[j], h) : 0u;
        }
        __syncthreads();
#pragma unroll
        for (int k = 0; k < P1_ITEMS; ++k) {
            if (bk[k] >= 0) {
                unsigned int pos = base[bk[k]] + rk[k];
                if (pos < (unsigned int)CAP2) {
                    bbuf[(size_t)bk[k] * CAP2 + pos] =
                        make_float4(px[k], py[k], pz[k], __int_as_float(cd[k]));
                }
            }
        }
        __syncthreads();
    }
}

__global__ __launch_bounds__(512) void p2_features(
        const unsigned int* __restrict__ gcnt,
        const float4* __restrict__ bbuf,
        float* __restrict__ out, int C) {
    __shared__ float sx[CAP2];                  // 24 KB  sorted x
    __shared__ float sy[CAP2];                  // 24 KB  sorted y
    __shared__ float sz[CAP2];                  // 24 KB  sorted z
    __shared__ unsigned int hist[NB_CL];
    __shared__ unsigned int basex[NB_CL];
    __shared__ unsigned int hist2[NB_CL];

    const int b   = blockIdx.x;
    const int tid = threadIdx.x;
    const int bcnt = min((int)gcnt[b], CAP2);
    const float4* src = bbuf + (size_t)b * CAP2;
    const float*  srcw = (const float*)src;     // scalar access to .w tags

    if (tid < NB_CL) { hist[tid] = 0; hist2[tid] = 0; }
    __syncthreads();

    // ---- pass A: histogram of 4B tags, ILP x4 ----
    for (int base_i = 0; base_i < bcnt; base_i += 2048) {
        int i0 = base_i + tid, i1 = i0 + 512, i2 = i0 + 1024, i3 = i0 + 1536;
        int c0 = -1, c1 = -1, c2 = -1, c3 = -1;
        if (i0 < bcnt) c0 = __float_as_int(srcw[4 * i0 + 3]) & (NB_CL - 1);
        if (i1 < bcnt) c1 = __float_as_int(srcw[4 * i1 + 3]) & (NB_CL - 1);
        if (i2 < bcnt) c2 = __float_as_int(srcw[4 * i2 + 3]) & (NB_CL - 1);
        if (i3 < bcnt) c3 = __float_as_int(srcw[4 * i3 + 3]) & (NB_CL - 1);
        if (c0 >= 0) atomicAdd(&hist[c0], 1u);
        if (c1 >= 0) atomicAdd(&hist[c1], 1u);
        if (c2 >= 0) atomicAdd(&hist[c2], 1u);
        if (c3 >= 0) atomicAdd(&hist[c3], 1u);
    }
    __syncthreads();

    // ---- exclusive scan over 64 entries (wave 0 shfl scan) ----
    if (tid < NB_CL) {
        unsigned int h = hist[tid];
        unsigned int inc = h;
#pragma unroll
        for (int off = 1; off < NB_CL; off <<= 1) {
            unsigned int t = __shfl_up(inc, off);
            if (tid >= off) inc += t;
        }
        basex[tid] = inc - h;
    }
    __syncthreads();

    // ---- pass B: sorted placement into LDS, ILP x4 ----
    for (int base_i = 0; base_i < bcnt; base_i += 2048) {
        int i0 = base_i + tid, i1 = i0 + 512, i2 = i0 + 1024, i3 = i0 + 1536;
        bool v0 = i0 < bcnt, v1 = i1 < bcnt, v2 = i2 < bcnt, v3 = i3 < bcnt;
        float4 p0, p1, p2, p3;
        if (v0) p0 = src[i0];
        if (v1) p1 = src[i1];
        if (v2) p2 = src[i2];
        if (v3) p3 = src[i3];
        if (v0) { int c = __float_as_int(p0.w) & (NB_CL - 1); unsigned r = atomicAdd(&hist2[c], 1u); unsigned q = basex[c] + r; sx[q] = p0.x; sy[q] = p0.y; sz[q] = p0.z; }
        if (v1) { int c = __float_as_int(p1.w) & (NB_CL - 1); unsigned r = atomicAdd(&hist2[c], 1u); unsigned q = basex[c] + r; sx[q] = p1.x; sy[q] = p1.y; sz[q] = p1.z; }
        if (v2) { int c = __float_as_int(p2.w) & (NB_CL - 1); unsigned r = atomicAdd(&hist2[c], 1u); unsigned q = basex[c] + r; sx[q] = p2.x; sy[q] = p2.y; sz[q] = p2.z; }
        if (v3) { int c = __float_as_int(p3.w) & (NB_CL - 1); unsigned r = atomicAdd(&hist2[c], 1u); unsigned q = basex[c] + r; sx[q] = p3.x; sy[q] = p3.y; sz[q] = p3.z; }
    }
    __syncthreads();

    // ---- barrier-free per-wave tail: 8 clusters per wave ----
    const int w    = tid >> 6;     // 0..7
    const int lane = tid & 63;

    // lane jj keeps cluster (w*8+jj)'s sums
    float k0 = 0.f, k1 = 0.f, k2 = 0.f, k3 = 0.f, k4 = 0.f;
    float k5 = 0.f, k6 = 0.f, k7 = 0.f, k8 = 0.f;

#pragma unroll
    for (int jj = 0; jj < 8; ++jj) {
        const int lc = (w << 3) | jj;
        const int n  = (int)hist[lc];
        const unsigned int nb = basex[lc];
        float s0 = 0.f, s1 = 0.f, s2 = 0.f, s3 = 0.f, s4 = 0.f;
        float s5 = 0.f, s6 = 0.f, s7 = 0.f, s8 = 0.f;
        for (int j = lane; j < n; j += 64) {
            float x = sx[nb + j], y = sy[nb + j], z = sz[nb + j];
            s0 += x;     s1 += y;     s2 += z;
            s3 += x * x; s4 += x * y; s5 += x * z;
            s6 += y * y; s7 += y * z; s8 += z * z;
        }
#pragma unroll
        for (int d = 32; d > 0; d >>= 1) {
            s0 += __shfl_xor(s0, d); s1 += __shfl_xor(s1, d); s2 += __shfl_xor(s2, d);
            s3 += __shfl_xor(s3, d); s4 += __shfl_xor(s4, d); s5 += __shfl_xor(s5, d);
            s6 += __shfl_xor(s6, d); s7 += __shfl_xor(s7, d); s8 += __shfl_xor(s8, d);
        }
        if (lane == jj) {
            k0 = s0; k1 = s1; k2 = s2; k3 = s3; k4 = s4;
            k5 = s5; k6 = s6; k7 = s7; k8 = s8;
        }
    }

    // ---- 8 f64 eigens on lanes 0..7 of this wave ----
    float cenx = 0.f, ceny = 0.f, cenz = 0.f;
    float evx = 0.f, evy = 0.f, evz = 0.f, fdw = 0.f;
    if (lane < 8) {
        const int lc = (w << 3) | lane;
        const int cl = b * NB_CL + lc;
        const int n  = (int)hist[lc];
        double dn = (double)n;
        double nd = (double)max(n, 1);
        double cx = (double)k0 / nd;
        double cy = (double)k1 / nd;
        double cz = (double)k2 / nd;

        double axx = (double)k3 - dn * cx * cx;
        double axy = (double)k4 - dn * cx * cy;
        double axz = (double)k5 - dn * cx * cz;
        double ayy = (double)k6 - dn * cy * cy;
        double ayz = (double)k7 - dn * cy * cz;
        double azz = (double)k8 - dn * cz * cz;

        double w0, w1, w2, v[3];
        eig3_sym(axx, axy, axz, ayy, ayz, azz, w0, w1, w2, v);

        double safe_w2 = (w2 > 0.0) ? w2 : 1.0;
        double isw = 1.0 / safe_w2;
        bool multi = (n >= 2);

        cenx = (float)cx; ceny = (float)cy; cenz = (float)cz;
        evx = (float)v[0]; evy = (float)v[1]; evz = (float)v[2];
        fdw = (float)(1.0 - w1 / safe_w2);

        if (cl < C) {
            float b3  = multi ? (float)(axx * isw) : 0.0f;
            float b4  = multi ? (float)(axy * isw) : 0.0f;
            float b5  = multi ? (float)(axz * isw) : 0.0f;
            float b7  = multi ? (float)(ayy * isw) : 0.0f;
            float b8  = multi ? (float)(ayz * isw) : 0.0f;
            float b11 = multi ? (float)(azz * isw) : 0.0f;
            float4* o = (float4*)(out + (size_t)cl * 16);
            o[0] = make_float4(cenx, ceny, cenz, b3);
            o[1] = make_float4(b4, b5, b4, b7);
            o[2] = make_float4(b8, b5, b8, b11);
        }
    }

    // ---- sc pass: shfl broadcast from lane jj, linear LDS reads ----
#pragma unroll 1
    for (int jj = 0; jj < 8; ++jj) {
        const int lc = (w << 3) | jj;
        const int cl = b * NB_CL + lc;
        if (cl >= C) continue;                  // wave-uniform
        const int n = (int)hist[lc];
        const unsigned int nb = basex[lc];
        const float fcx = __shfl(cenx, jj), fcy = __shfl(ceny, jj), fcz = __shfl(cenz, jj);
        const float vx = __shfl(evx, jj), vy = __shfl(evy, jj), vz = __shfl(evz, jj);
        const float dwv = __shfl(fdw, jj);
        float sc = 0.0f;
        for (int j = lane; j < n; j += 64) {
            float x = sx[nb + j] - fcx, y = sy[nb + j] - fcy, z = sz[nb + j] - fcz;
            float x0 = x * vx + y * vy + z * vz;
            float qx = x - x0 * vx, qy = y - x0 * vy, qz = z - x0 * vz;
            sc += x0 * sqrtf(qx * qx + qy * qy + qz * qz);
        }
#pragma unroll
        for (int d = 32; d > 0; d >>= 1) sc += __shfl_xor(sc, d);

        if (lane == 0) {
            float sgn = (sc < 0.0f) ? -1.0f : 1.0f;
            float m = (n >= 2) ? sgn * dwv : 0.0f;
            ((float4*)(out + (size_t)cl * 16))[3] =
                make_float4(vx * m, vy * m, vz * m, (float)n);
        }
    }
}

// ============================ fallback path (round-2) ======================
#define FXP_SCALE 131072.0f
#define FXP_BIAS  4194304
#define FXP_INV   (1.0 / 131072.0)

__device__ __forceinline__ unsigned int fxp_enc(float v) {
    return (unsigned int)(__float2int_rn(v * FXP_SCALE) + FXP_BIAS);
}
__device__ __forceinline__ double fxp_dec(unsigned int s, int n) {
    return (double)((long long)s - (long long)n * FXP_BIAS) * FXP_INV;
}

__global__ void k1_accum(const float* __restrict__ data,
                         const int* __restrict__ cid,
                         unsigned long long* __restrict__ acc,
                         int n_vox) {
    int stride = gridDim.x * blockDim.x;
    for (int i = blockIdx.x * blockDim.x + threadIdx.x; i < n_vox; i += stride) {
        int c = cid[i];
        const float* row = data + (size_t)i * 6;
        float x = row[1], y = row[2], z = row[3];
        unsigned long long* a = acc + (size_t)c * 5;
        unsigned long long p0 = ((unsigned long long)fxp_enc(y)     << 32) | fxp_enc(x);
        unsigned long long p1 = ((unsigned long long)fxp_enc(x * x) << 32) | fxp_enc(z);
        unsigned long long p2 = ((unsigned long long)fxp_enc(x * z) << 32) | fxp_enc(x * y);
        unsigned long long p3 = ((unsigned long long)fxp_enc(y * z) << 32) | fxp_enc(y * y);
        unsigned long long p4 = (1ULL << 32)                               | fxp_enc(z * z);
        atomicAdd(&a[0], p0);
        atomicAdd(&a[1], p1);
        atomicAdd(&a[2], p2);
        atomicAdd(&a[3], p3);
        atomicAdd(&a[4], p4);
    }
}

__global__ void k2_cluster(const unsigned long long* __restrict__ acc,
                           float* __restrict__ wf,
                           float* __restrict__ out, int C) {
    int c = blockIdx.x * blockDim.x + threadIdx.x;
    if (c >= C) return;
    const unsigned long long* a = acc + (size_t)c * 5;
    unsigned long long s0 = a[0], s1 = a[1], s2 = a[2], s3 = a[3], s4 = a[4];
    int n = (int)(s4 >> 32);

    double sx  = fxp_dec((unsigned int)s0,         n);
    double sy  = fxp_dec((unsigned int)(s0 >> 32), n);
    double sz  = fxp_dec((unsigned int)s1,         n);
    double sxx = fxp_dec((unsigned int)(s1 >> 32), n);
    double sxy = fxp_dec((unsigned int)s2,         n);
    double sxz = fxp_dec((unsigned int)(s2 >> 32), n);
    double syy = fxp_dec((unsigned int)s3,         n);
    double syz = fxp_dec((unsigned int)(s3 >> 32), n);
    double szz = fxp_dec((unsigned int)s4,         n);

    double nd = (double)max(n, 1);
    double cx = sx / nd, cy = sy / nd, cz = sz / nd;
    double dn = (double)n;
    double axx = sxx - dn * cx * cx;
    double axy = sxy - dn * cx * cy;
    double axz = sxz - dn * cx * cz;
    double ayy = syy - dn * cy * cy;
    double ayz = syz - dn * cy * cz;
    double azz = szz - dn * cz * cz;

    double w0, w1, w2, v[3];
    eig3_sym(axx, axy, axz, ayy, ayz, azz, w0, w1, w2, v);

    double safe_w2 = (w2 > 0.0) ? w2 : 1.0;
    double dirwt   = 1.0 - w1 / safe_w2;
    double isw     = 1.0 / safe_w2;
    bool multi = (n >= 2);

    float* o = out + (size_t)c * 16;
    o[0] = (float)cx; o[1] = (float)cy; o[2] = (float)cz;
    if (multi) {
        o[3]  = (float)(axx * isw); o[4]  = (float)(axy * isw); o[5]  = (float)(axz * isw);
        o[6]  = (float)(axy * isw); o[7]  = (float)(ayy * isw); o[8]  = (float)(ayz * isw);
        o[9]  = (float)(axz * isw); o[10] = (float)(ayz * isw); o[11] = (float)(azz * isw);
    } else {
        o[3] = 0.f; o[4] = 0.f; o[5] = 0.f; o[6] = 0.f; o[7] = 0.f;
        o[8] = 0.f; o[9] = 0.f; o[10] = 0.f; o[11] = 0.f;
    }
    o[15] = (float)n;

    wf[(size_t)C * 1 + c] = (float)cx;
    wf[(size_t)C * 2 + c] = (float)cy;
    wf[(size_t)C * 3 + c] = (float)cz;
    wf[(size_t)C * 4 + c] = (float)v[0];
    wf[(size_t)C * 5 + c] = (float)v[1];
    wf[(size_t)C * 6 + c] = (float)v[2];
    wf[(size_t)C * 7 + c] = (float)dirwt;
}

__global__ void k3_sc(const float* __restrict__ data,
                      const int* __restrict__ cid,
                      float* __restrict__ wf,
                      int n_vox, int C) {
    const float* cenx = wf + (size_t)C * 1;
    const float* ceny = wf + (size_t)C * 2;
    const float* cenz = wf + (size_t)C * 3;
    const float* v0x  = wf + (size_t)C * 4;
    const float* v0y  = wf + (size_t)C * 5;
    const float* v0z  = wf + (size_t)C * 6;
    float* sc = wf;
    int stride = gridDim.x * blockDim.x;
    for (int i = blockIdx.x * blockDim.x + threadIdx.x; i < n_vox; i += stride) {
        int c = cid[i];
        const float* row = data + (size_t)i * 6;
        float x = row[1] - cenx[c];
        float y = row[2] - ceny[c];
        float z = row[3] - cenz[c];
        float vx = v0x[c], vy = v0y[c], vz = v0z[c];
        float x0 = x * vx + y * vy + z * vz;
        float px = x - x0 * vx;
        float py = y - x0 * vy;
        float pz = z - x0 * vz;
        atomicAdd(&sc[c], x0 * sqrtf(px * px + py * py + pz * pz));
    }
}

__global__ void k4_final(const unsigned long long* __restrict__ acc,
                         const float* __restrict__ wf,
                         float* __restrict__ out, int C) {
    int c = blockIdx.x * blockDim.x + threadIdx.x;
    if (c >= C) return;
    int n = (int)(acc[(size_t)c * 5 + 4] >> 32);
    float scv = wf[c];
    float vx  = wf[(size_t)C * 4 + c];
    float vy  = wf[(size_t)C * 5 + c];
    float vz  = wf[(size_t)C * 6 + c];
    float dir = wf[(size_t)C * 7 + c];
    float sgn = (scv < 0.0f) ? -1.0f : 1.0f;
    float m = (n >= 2) ? sgn * dir : 0.0f;
    float* o = out + (size_t)c * 16;
    o[12] = vx * m;
    o[13] = vy * m;
    o[14] = vz * m;
}

// ============================ launch =======================================
extern "C" void kernel_launch(void* const* d_in, const int* in_sizes, int n_in,
                              void* d_out, int out_size, void* d_ws, size_t ws_size,
                              hipStream_t stream) {
    const float* data = (const float*)d_in[0];
    const int*   cid  = (const int*)d_in[1];
    float* out = (float*)d_out;

    int n_vox = in_sizes[1];
    int C     = out_size / 16;

    int nbuckets = (C + NB_CL - 1) / NB_CL;
    long long expected = (C > 0) ? (long long)n_vox * NB_CL / C : 0;
    size_t gcnt_bytes = ((size_t)nbuckets * 4 + 255) & ~(size_t)255;
    size_t bbuf_bytes = (size_t)nbuckets * CAP2 * 16;
    size_t need = gcnt_bytes + bbuf_bytes;

    if (C > 0 && nbuckets <= NB_MAX && expected <= (CAP2 * 7) / 8 && ws_size >= need) {
        unsigned int* gcnt = (unsigned int*)d_ws;
        float4* bbuf = (float4*)((char*)d_ws + gcnt_bytes);
        hipMemsetAsync(d_ws, 0, gcnt_bytes, stream);
        int total_rounds = (n_vox + P1_BLOCK * P1_ITEMS - 1) / (P1_BLOCK * P1_ITEMS);
        int p1_blocks = total_rounds < 1024 ? total_rounds : 1024;
        if (p1_blocks < 1) p1_blocks = 1;
        p1_bucket<<<p1_blocks, P1_BLOCK, 0, stream>>>(data, cid, gcnt, bbuf, n_vox, nbuckets);
        p2_features<<<nbuckets, 512, 0, stream>>>(gcnt, bbuf, out, C);
    } else {
        unsigned long long* acc = (unsigned long long*)d_ws;
        float* wf = (float*)((char*)d_ws + (size_t)C * 40);
        hipMemsetAsync(d_ws, 0, (size_t)C * 44, stream);
        const int vox_blocks = 4096;
        const int cl_blocks  = (C + 255) / 256;
        k1_accum<<<vox_blocks, 256, 0, stream>>>(data, cid, acc, n_vox);
        k2_cluster<<<cl_blocks, 256, 0, stream>>>(acc, wf, out, C);
        k3_sc<<<vox_blocks, 256, 0, stream>>>(data, cid, wf, n_vox, C);
        k4_final<<<cl_blocks, 256, 0, stream>>>(acc, wf, out, C);
    }
}

// Round 13
// 125.769 us; speedup vs baseline: 1.4254x; 1.1200x over previous
//
#include <hip/hip_runtime.h>
#include <math.h>

// ---------------------------------------------------------------------------
// ClustGeoNodeEncoder via two-level bucket decomposition.
//
// Measured walls: global atomics ~16-23 G ops/s (r2-r4); LDS-atomic moments at
// low parallelism serialize (r5); redundant f64 eigen VALU-heavy (r6); bucket
// splitting kills gather locality (r7); L2 thrash at 384KB windows (r8); byte-
// scatter write amp (r9); random 16B LDS gathers conflict (r10); p2 latency-
// bound at 1 blk/CU (r11); p1 scattered stores = 2.4x write amp, store-bound
// (r12: WRITE 151MB for 64MB payload).
// Design (r13):
//   p1_bucket   : 8192-pt rounds. ranks via LDS atomics -> block scan ->
//                 SORT THE ROUND IN LDS (128KB) -> linear write-out: lanes
//                 write consecutive sorted positions -> coalesced full-line
//                 stores (amp ~1.15x). Full cid rides in .w.
//   p2_features : r12's barrier-free version (512 thr, 74.5KB LDS,
//                 ILP x4 streams, per-wave 8-cluster tail).
// Fallback (small ws): round-2 packed u64 fixed-point pipeline.
// ---------------------------------------------------------------------------

#define NB_CL   64         // clusters per bucket
#define CAP2    6144       // per-bucket point capacity (mean 5120, +14 sigma)
#define NB_MAX  1024       // max buckets supported by p1's LDS histogram

// ========================= shared: 3x3 symmetric eigen =====================
__device__ inline void eig3_sym(double a00, double a01, double a02,
                                double a11, double a12, double a22,
                                double& w0, double& w1, double& w2,
                                double v[3]) {
    double p1 = a01 * a01 + a02 * a02 + a12 * a12;
    double q  = (a00 + a11 + a22) / 3.0;
    double d0 = a00 - q, d1 = a11 - q, d2 = a22 - q;
    double p2 = d0 * d0 + d1 * d1 + d2 * d2 + 2.0 * p1;
    double p  = sqrt(p2 / 6.0);
    if (p < 1e-300) {
        w0 = w1 = w2 = q;
        v[0] = 0.0; v[1] = 0.0; v[2] = 1.0;
        return;
    }
    double ip = 1.0 / p;
    double b00 = d0 * ip, b11 = d1 * ip, b22 = d2 * ip;
    double b01 = a01 * ip, b02 = a02 * ip, b12 = a12 * ip;
    double detB = b00 * (b11 * b22 - b12 * b12)
                - b01 * (b01 * b22 - b12 * b02)
                + b02 * (b01 * b12 - b11 * b02);
    double r = detB * 0.5;
    r = fmin(1.0, fmax(-1.0, r));
    double phi = acos(r) / 3.0;
    w2 = q + 2.0 * p * cos(phi);
    w0 = q + 2.0 * p * cos(phi + 2.0943951023931953);  // +2*pi/3
    w1 = 3.0 * q - w2 - w0;

    double r0x = a00 - w2, r0y = a01,       r0z = a02;
    double r1x = a01,      r1y = a11 - w2,  r1z = a12;
    double r2x = a02,      r2y = a12,       r2z = a22 - w2;

    double c0x = r0y * r1z - r0z * r1y;
    double c0y = r0z * r1x - r0x * r1z;
    double c0z = r0x * r1y - r0y * r1x;
    double n0  = c0x * c0x + c0y * c0y + c0z * c0z;

    double c1x = r0y * r2z - r0z * r2y;
    double c1y = r0z * r2x - r0x * r2z;
    double c1z = r0x * r2y - r0y * r2x;
    double n1  = c1x * c1x + c1y * c1y + c1z * c1z;

    double c2x = r1y * r2z - r1z * r2y;
    double c2y = r1z * r2x - r1x * r2z;
    double c2z = r1x * r2y - r1y * r2x;
    double n2  = c2x * c2x + c2y * c2y + c2z * c2z;

    double vx, vy, vz, nn;
    if (n0 >= n1 && n0 >= n2) { vx = c0x; vy = c0y; vz = c0z; nn = n0; }
    else if (n1 >= n2)        { vx = c1x; vy = c1y; vz = c1z; nn = n1; }
    else                      { vx = c2x; vy = c2y; vz = c2z; nn = n2; }
    if (nn < 1e-300) {
        v[0] = 0.0; v[1] = 0.0; v[2] = 1.0;
        return;
    }
    double inv = rsqrt(nn);
    v[0] = vx * inv; v[1] = vy * inv; v[2] = vz * inv;
}

// ============================ primary path =================================
#define P1_BLOCK 1024
#define P1_ITEMS 8     // voxels per thread per round -> 8192 per block-round
#define P1_ROUND (P1_BLOCK * P1_ITEMS)

__global__ __launch_bounds__(P1_BLOCK) void p1_bucket(
        const float* __restrict__ data,
        const int* __restrict__ cid,
        unsigned int* __restrict__ gcnt,     // [nbuckets]
        float4* __restrict__ bbuf,           // [nb*CAP2]
        int n_vox, int nbuckets) {
    __shared__ float4 ss[P1_ROUND];          // 128 KB sorted round buffer
    __shared__ unsigned int hist[NB_MAX];    // 4 KB
    __shared__ unsigned int lbase[NB_MAX];   // 4 KB  exclusive scan
    __shared__ unsigned int gbase[NB_MAX];   // 4 KB  global bases
    const int tid = threadIdx.x;
    const int total_rounds = (n_vox + P1_ROUND - 1) / P1_ROUND;

    for (int r = blockIdx.x; r < total_rounds; r += gridDim.x) {
        const int start = r * P1_ROUND;
        const int rtotal = min(P1_ROUND, n_vox - start);
        for (int j = tid; j < nbuckets; j += P1_BLOCK) hist[j] = 0;
        __syncthreads();

        int   bk[P1_ITEMS];
        int   cd[P1_ITEMS];
        float px[P1_ITEMS], py[P1_ITEMS], pz[P1_ITEMS];
        unsigned int rk[P1_ITEMS];
#pragma unroll
        for (int k = 0; k < P1_ITEMS; ++k) {
            int i = start + tid + k * P1_BLOCK;   // coalesced lane pattern
            if (i < n_vox) {
                int c = cid[i];
                cd[k] = c;
                bk[k] = c >> 6;
                const float* row = data + (size_t)i * 6;
                px[k] = row[1]; py[k] = row[2]; pz[k] = row[3];
                rk[k] = atomicAdd(&hist[bk[k]], 1u);   // local rank
            } else {
                bk[k] = -1;
            }
        }
        __syncthreads();

        // exclusive scan of hist -> lbase (Hillis-Steele over nbuckets)
        for (int j = tid; j < nbuckets; j += P1_BLOCK) lbase[j] = hist[j];
        __syncthreads();
        for (int off = 1; off < nbuckets; off <<= 1) {
            unsigned int v = 0;
            for (int j = tid; j < nbuckets; j += P1_BLOCK)
                v = (j >= off) ? lbase[j - off] : 0u;   // P1_BLOCK>=nbuckets: single j
            __syncthreads();
            for (int j = tid; j < nbuckets; j += P1_BLOCK)
                if (j >= off) lbase[j] += v;
            __syncthreads();
        }
        for (int j = tid; j < nbuckets; j += P1_BLOCK) {
            unsigned int h = hist[j];
            lbase[j] -= h;                       // inclusive -> exclusive
            gbase[j] = h ? atomicAdd(&gcnt[j], h) : 0u;
        }
        __syncthreads();

        // scatter the round into LDS in bucket-sorted order
#pragma unroll
        for (int k = 0; k < P1_ITEMS; ++k) {
            if (bk[k] >= 0) {
                unsigned int p = lbase[bk[k]] + rk[k];
                ss[p] = make_float4(px[k], py[k], pz[k], __int_as_float(cd[k]));
            }
        }
        __syncthreads();

        // linear write-out: consecutive lanes -> consecutive positions
        for (int j = tid; j < rtotal; j += P1_BLOCK) {
            float4 p = ss[j];
            int c  = __float_as_int(p.w);
            int bb = c >> 6;
            unsigned int off = gbase[bb] + ((unsigned)j - lbase[bb]);
            if (off < (unsigned int)CAP2)
                bbuf[(size_t)bb * CAP2 + off] = p;   // p2 masks .w with &63
        }
        __syncthreads();
    }
}

__global__ __launch_bounds__(512) void p2_features(
        const unsigned int* __restrict__ gcnt,
        const float4* __restrict__ bbuf,
        float* __restrict__ out, int C) {
    __shared__ float sx[CAP2];                  // 24 KB  sorted x
    __shared__ float sy[CAP2];                  // 24 KB  sorted y
    __shared__ float sz[CAP2];                  // 24 KB  sorted z
    __shared__ unsigned int hist[NB_CL];
    __shared__ unsigned int basex[NB_CL];
    __shared__ unsigned int hist2[NB_CL];

    const int b   = blockIdx.x;
    const int tid = threadIdx.x;
    const int bcnt = min((int)gcnt[b], CAP2);
    const float4* src = bbuf + (size_t)b * CAP2;
    const float*  srcw = (const float*)src;     // scalar access to .w tags

    if (tid < NB_CL) { hist[tid] = 0; hist2[tid] = 0; }
    __syncthreads();

    // ---- pass A: histogram of 4B tags, ILP x4 ----
    for (int base_i = 0; base_i < bcnt; base_i += 2048) {
        int i0 = base_i + tid, i1 = i0 + 512, i2 = i0 + 1024, i3 = i0 + 1536;
        int c0 = -1, c1 = -1, c2 = -1, c3 = -1;
        if (i0 < bcnt) c0 = __float_as_int(srcw[4 * i0 + 3]) & (NB_CL - 1);
        if (i1 < bcnt) c1 = __float_as_int(srcw[4 * i1 + 3]) & (NB_CL - 1);
        if (i2 < bcnt) c2 = __float_as_int(srcw[4 * i2 + 3]) & (NB_CL - 1);
        if (i3 < bcnt) c3 = __float_as_int(srcw[4 * i3 + 3]) & (NB_CL - 1);
        if (c0 >= 0) atomicAdd(&hist[c0], 1u);
        if (c1 >= 0) atomicAdd(&hist[c1], 1u);
        if (c2 >= 0) atomicAdd(&hist[c2], 1u);
        if (c3 >= 0) atomicAdd(&hist[c3], 1u);
    }
    __syncthreads();

    // ---- exclusive scan over 64 entries (wave 0 shfl scan) ----
    if (tid < NB_CL) {
        unsigned int h = hist[tid];
        unsigned int inc = h;
#pragma unroll
        for (int off = 1; off < NB_CL; off <<= 1) {
            unsigned int t = __shfl_up(inc, off);
            if (tid >= off) inc += t;
        }
        basex[tid] = inc - h;
    }
    __syncthreads();

    // ---- pass B: sorted placement into LDS, ILP x4 ----
    for (int base_i = 0; base_i < bcnt; base_i += 2048) {
        int i0 = base_i + tid, i1 = i0 + 512, i2 = i0 + 1024, i3 = i0 + 1536;
        bool v0 = i0 < bcnt, v1 = i1 < bcnt, v2 = i2 < bcnt, v3 = i3 < bcnt;
        float4 p0, p1, p2, p3;
        if (v0) p0 = src[i0];
        if (v1) p1 = src[i1];
        if (v2) p2 = src[i2];
        if (v3) p3 = src[i3];
        if (v0) { int c = __float_as_int(p0.w) & (NB_CL - 1); unsigned r = atomicAdd(&hist2[c], 1u); unsigned q = basex[c] + r; sx[q] = p0.x; sy[q] = p0.y; sz[q] = p0.z; }
        if (v1) { int c = __float_as_int(p1.w) & (NB_CL - 1); unsigned r = atomicAdd(&hist2[c], 1u); unsigned q = basex[c] + r; sx[q] = p1.x; sy[q] = p1.y; sz[q] = p1.z; }
        if (v2) { int c = __float_as_int(p2.w) & (NB_CL - 1); unsigned r = atomicAdd(&hist2[c], 1u); unsigned q = basex[c] + r; sx[q] = p2.x; sy[q] = p2.y; sz[q] = p2.z; }
        if (v3) { int c = __float_as_int(p3.w) & (NB_CL - 1); unsigned r = atomicAdd(&hist2[c], 1u); unsigned q = basex[c] + r; sx[q] = p3.x; sy[q] = p3.y; sz[q] = p3.z; }
    }
    __syncthreads();

    // ---- barrier-free per-wave tail: 8 clusters per wave ----
    const int w    = tid >> 6;     // 0..7
    const int lane = tid & 63;

    float k0 = 0.f, k1 = 0.f, k2 = 0.f, k3 = 0.f, k4 = 0.f;
    float k5 = 0.f, k6 = 0.f, k7 = 0.f, k8 = 0.f;

#pragma unroll
    for (int jj = 0; jj < 8; ++jj) {
        const int lc = (w << 3) | jj;
        const int n  = (int)hist[lc];
        const unsigned int nb = basex[lc];
        float s0 = 0.f, s1 = 0.f, s2 = 0.f, s3 = 0.f, s4 = 0.f;
        float s5 = 0.f, s6 = 0.f, s7 = 0.f, s8 = 0.f;
        for (int j = lane; j < n; j += 64) {
            float x = sx[nb + j], y = sy[nb + j], z = sz[nb + j];
            s0 += x;     s1 += y;     s2 += z;
            s3 += x * x; s4 += x * y; s5 += x * z;
            s6 += y * y; s7 += y * z; s8 += z * z;
        }
#pragma unroll
        for (int d = 32; d > 0; d >>= 1) {
            s0 += __shfl_xor(s0, d); s1 += __shfl_xor(s1, d); s2 += __shfl_xor(s2, d);
            s3 += __shfl_xor(s3, d); s4 += __shfl_xor(s4, d); s5 += __shfl_xor(s5, d);
            s6 += __shfl_xor(s6, d); s7 += __shfl_xor(s7, d); s8 += __shfl_xor(s8, d);
        }
        if (lane == jj) {
            k0 = s0; k1 = s1; k2 = s2; k3 = s3; k4 = s4;
            k5 = s5; k6 = s6; k7 = s7; k8 = s8;
        }
    }

    // ---- 8 f64 eigens on lanes 0..7 of this wave ----
    float cenx = 0.f, ceny = 0.f, cenz = 0.f;
    float evx = 0.f, evy = 0.f, evz = 0.f, fdw = 0.f;
    if (lane < 8) {
        const int lc = (w << 3) | lane;
        const int cl = b * NB_CL + lc;
        const int n  = (int)hist[lc];
        double dn = (double)n;
        double nd = (double)max(n, 1);
        double cx = (double)k0 / nd;
        double cy = (double)k1 / nd;
        double cz = (double)k2 / nd;

        double axx = (double)k3 - dn * cx * cx;
        double axy = (double)k4 - dn * cx * cy;
        double axz = (double)k5 - dn * cx * cz;
        double ayy = (double)k6 - dn * cy * cy;
        double ayz = (double)k7 - dn * cy * cz;
        double azz = (double)k8 - dn * cz * cz;

        double w0, w1, w2, v[3];
        eig3_sym(axx, axy, axz, ayy, ayz, azz, w0, w1, w2, v);

        double safe_w2 = (w2 > 0.0) ? w2 : 1.0;
        double isw = 1.0 / safe_w2;
        bool multi = (n >= 2);

        cenx = (float)cx; ceny = (float)cy; cenz = (float)cz;
        evx = (float)v[0]; evy = (float)v[1]; evz = (float)v[2];
        fdw = (float)(1.0 - w1 / safe_w2);

        if (cl < C) {
            float b3  = multi ? (float)(axx * isw) : 0.0f;
            float b4  = multi ? (float)(axy * isw) : 0.0f;
            float b5  = multi ? (float)(axz * isw) : 0.0f;
            float b7  = multi ? (float)(ayy * isw) : 0.0f;
            float b8  = multi ? (float)(ayz * isw) : 0.0f;
            float b11 = multi ? (float)(azz * isw) : 0.0f;
            float4* o = (float4*)(out + (size_t)cl * 16);
            o[0] = make_float4(cenx, ceny, cenz, b3);
            o[1] = make_float4(b4, b5, b4, b7);
            o[2] = make_float4(b8, b5, b8, b11);
        }
    }

    // ---- sc pass: shfl broadcast from lane jj, linear LDS reads ----
#pragma unroll 1
    for (int jj = 0; jj < 8; ++jj) {
        const int lc = (w << 3) | jj;
        const int cl = b * NB_CL + lc;
        if (cl >= C) continue;                  // wave-uniform
        const int n = (int)hist[lc];
        const unsigned int nb = basex[lc];
        const float fcx = __shfl(cenx, jj), fcy = __shfl(ceny, jj), fcz = __shfl(cenz, jj);
        const float vx = __shfl(evx, jj), vy = __shfl(evy, jj), vz = __shfl(evz, jj);
        const float dwv = __shfl(fdw, jj);
        float sc = 0.0f;
        for (int j = lane; j < n; j += 64) {
            float x = sx[nb + j] - fcx, y = sy[nb + j] - fcy, z = sz[nb + j] - fcz;
            float x0 = x * vx + y * vy + z * vz;
            float qx = x - x0 * vx, qy = y - x0 * vy, qz = z - x0 * vz;
            sc += x0 * sqrtf(qx * qx + qy * qy + qz * qz);
        }
#pragma unroll
        for (int d = 32; d > 0; d >>= 1) sc += __shfl_xor(sc, d);

        if (lane == 0) {
            float sgn = (sc < 0.0f) ? -1.0f : 1.0f;
            float m = (n >= 2) ? sgn * dwv : 0.0f;
            ((float4*)(out + (size_t)cl * 16))[3] =
                make_float4(vx * m, vy * m, vz * m, (float)n);
        }
    }
}

// ============================ fallback path (round-2) ======================
#define FXP_SCALE 131072.0f
#define FXP_BIAS  4194304
#define FXP_INV   (1.0 / 131072.0)

__device__ __forceinline__ unsigned int fxp_enc(float v) {
    return (unsigned int)(__float2int_rn(v * FXP_SCALE) + FXP_BIAS);
}
__device__ __forceinline__ double fxp_dec(unsigned int s, int n) {
    return (double)((long long)s - (long long)n * FXP_BIAS) * FXP_INV;
}

__global__ void k1_accum(const float* __restrict__ data,
                         const int* __restrict__ cid,
                         unsigned long long* __restrict__ acc,
                         int n_vox) {
    int stride = gridDim.x * blockDim.x;
    for (int i = blockIdx.x * blockDim.x + threadIdx.x; i < n_vox; i += stride) {
        int c = cid[i];
        const float* row = data + (size_t)i * 6;
        float x = row[1], y = row[2], z = row[3];
        unsigned long long* a = acc + (size_t)c * 5;
        unsigned long long p0 = ((unsigned long long)fxp_enc(y)     << 32) | fxp_enc(x);
        unsigned long long p1 = ((unsigned long long)fxp_enc(x * x) << 32) | fxp_enc(z);
        unsigned long long p2 = ((unsigned long long)fxp_enc(x * z) << 32) | fxp_enc(x * y);
        unsigned long long p3 = ((unsigned long long)fxp_enc(y * z) << 32) | fxp_enc(y * y);
        unsigned long long p4 = (1ULL << 32)                               | fxp_enc(z * z);
        atomicAdd(&a[0], p0);
        atomicAdd(&a[1], p1);
        atomicAdd(&a[2], p2);
        atomicAdd(&a[3], p3);
        atomicAdd(&a[4], p4);
    }
}

__global__ void k2_cluster(const unsigned long long* __restrict__ acc,
                           float* __restrict__ wf,
                           float* __restrict__ out, int C) {
    int c = blockIdx.x * blockDim.x + threadIdx.x;
    if (c >= C) return;
    const unsigned long long* a = acc + (size_t)c * 5;
    unsigned long long s0 = a[0], s1 = a[1], s2 = a[2], s3 = a[3], s4 = a[4];
    int n = (int)(s4 >> 32);

    double sx  = fxp_dec((unsigned int)s0,         n);
    double sy  = fxp_dec((unsigned int)(s0 >> 32), n);
    double sz  = fxp_dec((unsigned int)s1,         n);
    double sxx = fxp_dec((unsigned int)(s1 >> 32), n);
    double sxy = fxp_dec((unsigned int)s2,         n);
    double sxz = fxp_dec((unsigned int)(s2 >> 32), n);
    double syy = fxp_dec((unsigned int)s3,         n);
    double syz = fxp_dec((unsigned int)(s3 >> 32), n);
    double szz = fxp_dec((unsigned int)s4,         n);

    double nd = (double)max(n, 1);
    double cx = sx / nd, cy = sy / nd, cz = sz / nd;
    double dn = (double)n;
    double axx = sxx - dn * cx * cx;
    double axy = sxy - dn * cx * cy;
    double axz = sxz - dn * cx * cz;
    double ayy = syy - dn * cy * cy;
    double ayz = syz - dn * cy * cz;
    double azz = szz - dn * cz * cz;

    double w0, w1, w2, v[3];
    eig3_sym(axx, axy, axz, ayy, ayz, azz, w0, w1, w2, v);

    double safe_w2 = (w2 > 0.0) ? w2 : 1.0;
    double dirwt   = 1.0 - w1 / safe_w2;
    double isw     = 1.0 / safe_w2;
    bool multi = (n >= 2);

    float* o = out + (size_t)c * 16;
    o[0] = (float)cx; o[1] = (float)cy; o[2] = (float)cz;
    if (multi) {
        o[3]  = (float)(axx * isw); o[4]  = (float)(axy * isw); o[5]  = (float)(axz * isw);
        o[6]  = (float)(axy * isw); o[7]  = (float)(ayy * isw); o[8]  = (float)(ayz * isw);
        o[9]  = (float)(axz * isw); o[10] = (float)(ayz * isw); o[11] = (float)(azz * isw);
    } else {
        o[3] = 0.f; o[4] = 0.f; o[5] = 0.f; o[6] = 0.f; o[7] = 0.f;
        o[8] = 0.f; o[9] = 0.f; o[10] = 0.f; o[11] = 0.f;
    }
    o[15] = (float)n;

    wf[(size_t)C * 1 + c] = (float)cx;
    wf[(size_t)C * 2 + c] = (float)cy;
    wf[(size_t)C * 3 + c] = (float)cz;
    wf[(size_t)C * 4 + c] = (float)v[0];
    wf[(size_t)C * 5 + c] = (float)v[1];
    wf[(size_t)C * 6 + c] = (float)v[2];
    wf[(size_t)C * 7 + c] = (float)dirwt;
}

__global__ void k3_sc(const float* __restrict__ data,
                      const int* __restrict__ cid,
                      float* __restrict__ wf,
                      int n_vox, int C) {
    const float* cenx = wf + (size_t)C * 1;
    const float* ceny = wf + (size_t)C * 2;
    const float* cenz = wf + (size_t)C * 3;
    const float* v0x  = wf + (size_t)C * 4;
    const float* v0y  = wf + (size_t)C * 5;
    const float* v0z  = wf + (size_t)C * 6;
    float* sc = wf;
    int stride = gridDim.x * blockDim.x;
    for (int i = blockIdx.x * blockDim.x + threadIdx.x; i < n_vox; i += stride) {
        int c = cid[i];
        const float* row = data + (size_t)i * 6;
        float x = row[1] - cenx[c];
        float y = row[2] - ceny[c];
        float z = row[3] - cenz[c];
        float vx = v0x[c], vy = v0y[c], vz = v0z[c];
        float x0 = x * vx + y * vy + z * vz;
        float px = x - x0 * vx;
        float py = y - x0 * vy;
        float pz = z - x0 * vz;
        atomicAdd(&sc[c], x0 * sqrtf(px * px + py * py + pz * pz));
    }
}

__global__ void k4_final(const unsigned long long* __restrict__ acc,
                         const float* __restrict__ wf,
                         float* __restrict__ out, int C) {
    int c = blockIdx.x * blockDim.x + threadIdx.x;
    if (c >= C) return;
    int n = (int)(acc[(size_t)c * 5 + 4] >> 32);
    float scv = wf[c];
    float vx  = wf[(size_t)C * 4 + c];
    float vy  = wf[(size_t)C * 5 + c];
    float vz  = wf[(size_t)C * 6 + c];
    float dir = wf[(size_t)C * 7 + c];
    float sgn = (scv < 0.0f) ? -1.0f : 1.0f;
    float m = (n >= 2) ? sgn * dir : 0.0f;
    float* o = out + (size_t)c * 16;
    o[12] = vx * m;
    o[13] = vy * m;
    o[14] = vz * m;
}

// ============================ launch =======================================
extern "C" void kernel_launch(void* const* d_in, const int* in_sizes, int n_in,
                              void* d_out, int out_size, void* d_ws, size_t ws_size,
                              hipStream_t stream) {
    const float* data = (const float*)d_in[0];
    const int*   cid  = (const int*)d_in[1];
    float* out = (float*)d_out;

    int n_vox = in_sizes[1];
    int C     = out_size / 16;

    int nbuckets = (C + NB_CL - 1) / NB_CL;
    long long expected = (C > 0) ? (long long)n_vox * NB_CL / C : 0;
    size_t gcnt_bytes = ((size_t)nbuckets * 4 + 255) & ~(size_t)255;
    size_t bbuf_bytes = (size_t)nbuckets * CAP2 * 16;
    size_t need = gcnt_bytes + bbuf_bytes;

    if (C > 0 && nbuckets <= NB_MAX && expected <= (CAP2 * 7) / 8 && ws_size >= need) {
        unsigned int* gcnt = (unsigned int*)d_ws;
        float4* bbuf = (float4*)((char*)d_ws + gcnt_bytes);
        hipMemsetAsync(d_ws, 0, gcnt_bytes, stream);
        int total_rounds = (n_vox + P1_ROUND - 1) / P1_ROUND;
        int p1_blocks = total_rounds < 512 ? total_rounds : 512;
        if (p1_blocks < 1) p1_blocks = 1;
        p1_bucket<<<p1_blocks, P1_BLOCK, 0, stream>>>(data, cid, gcnt, bbuf, n_vox, nbuckets);
        p2_features<<<nbuckets, 512, 0, stream>>>(gcnt, bbuf, out, C);
    } else {
        unsigned long long* acc = (unsigned long long*)d_ws;
        float* wf = (float*)((char*)d_ws + (size_t)C * 40);
        hipMemsetAsync(d_ws, 0, (size_t)C * 44, stream);
        const int vox_blocks = 4096;
        const int cl_blocks  = (C + 255) / 256;
        k1_accum<<<vox_blocks, 256, 0, stream>>>(data, cid, acc, n_vox);
        k2_cluster<<<cl_blocks, 256, 0, stream>>>(acc, wf, out, C);
        k3_sc<<<vox_blocks, 256, 0, stream>>>(data, cid, wf, n_vox, C);
        k4_final<<<cl_blocks, 256, 0, stream>>>(acc, wf, out, C);
    }
}

// Round 14
// 123.980 us; speedup vs baseline: 1.4460x; 1.0144x over previous
//
#include <hip/hip_runtime.h>
#include <math.h>

// ---------------------------------------------------------------------------
// ClustGeoNodeEncoder via two-level bucket decomposition.
//
// Measured walls: global atomics ~16-23 G ops/s (r2-r4); LDS-atomic moments at
// low parallelism serialize (r5); redundant f64 eigen VALU-heavy (r6); bucket
// splitting kills gather locality (r7); L2 thrash at 384KB windows (r8); RANDOM
// byte-scatter write amp (r9); random 16B LDS gathers conflict (r10); p2
// latency-bound at 1 blk/CU (r11); p1 scattered stores 2.4x write amp (r12,
// fixed r13 by LDS round-sort); p2 pass-A strided 4B tag loads drag full lines
// (r13: 77us, latency-bound).
// Design (r14):
//   p1_bucket   : r13's LDS round-sort + linear write-out; ALSO writes the
//                 6-bit tag into lcb[] in the same sorted order (coalesced
//                 runs, ~1.15x amp — NOT r9's random scatter).
//   p2_features : pass A histograms from lcb via uint4 (16 tags/load, 5MB
//                 total); pass B streams float4 once; barrier-free per-wave
//                 tail (8 clusters/wave, lane-parallel f64 eigen).
// Fallback (small ws): round-2 packed u64 fixed-point pipeline.
// ---------------------------------------------------------------------------

#define NB_CL   64         // clusters per bucket
#define CAP2    6144       // per-bucket point capacity (mean 5120, +14 sigma)
#define NB_MAX  1024       // max buckets supported by p1's LDS histogram

// ========================= shared: 3x3 symmetric eigen =====================
__device__ inline void eig3_sym(double a00, double a01, double a02,
                                double a11, double a12, double a22,
                                double& w0, double& w1, double& w2,
                                double v[3]) {
    double p1 = a01 * a01 + a02 * a02 + a12 * a12;
    double q  = (a00 + a11 + a22) / 3.0;
    double d0 = a00 - q, d1 = a11 - q, d2 = a22 - q;
    double p2 = d0 * d0 + d1 * d1 + d2 * d2 + 2.0 * p1;
    double p  = sqrt(p2 / 6.0);
    if (p < 1e-300) {
        w0 = w1 = w2 = q;
        v[0] = 0.0; v[1] = 0.0; v[2] = 1.0;
        return;
    }
    double ip = 1.0 / p;
    double b00 = d0 * ip, b11 = d1 * ip, b22 = d2 * ip;
    double b01 = a01 * ip, b02 = a02 * ip, b12 = a12 * ip;
    double detB = b00 * (b11 * b22 - b12 * b12)
                - b01 * (b01 * b22 - b12 * b02)
                + b02 * (b01 * b12 - b11 * b02);
    double r = detB * 0.5;
    r = fmin(1.0, fmax(-1.0, r));
    double phi = acos(r) / 3.0;
    w2 = q + 2.0 * p * cos(phi);
    w0 = q + 2.0 * p * cos(phi + 2.0943951023931953);  // +2*pi/3
    w1 = 3.0 * q - w2 - w0;

    double r0x = a00 - w2, r0y = a01,       r0z = a02;
    double r1x = a01,      r1y = a11 - w2,  r1z = a12;
    double r2x = a02,      r2y = a12,       r2z = a22 - w2;

    double c0x = r0y * r1z - r0z * r1y;
    double c0y = r0z * r1x - r0x * r1z;
    double c0z = r0x * r1y - r0y * r1x;
    double n0  = c0x * c0x + c0y * c0y + c0z * c0z;

    double c1x = r0y * r2z - r0z * r2y;
    double c1y = r0z * r2x - r0x * r2z;
    double c1z = r0x * r2y - r0y * r2x;
    double n1  = c1x * c1x + c1y * c1y + c1z * c1z;

    double c2x = r1y * r2z - r1z * r2y;
    double c2y = r1z * r2x - r1x * r2z;
    double c2z = r1x * r2y - r1y * r2x;
    double n2  = c2x * c2x + c2y * c2y + c2z * c2z;

    double vx, vy, vz, nn;
    if (n0 >= n1 && n0 >= n2) { vx = c0x; vy = c0y; vz = c0z; nn = n0; }
    else if (n1 >= n2)        { vx = c1x; vy = c1y; vz = c1z; nn = n1; }
    else                      { vx = c2x; vy = c2y; vz = c2z; nn = n2; }
    if (nn < 1e-300) {
        v[0] = 0.0; v[1] = 0.0; v[2] = 1.0;
        return;
    }
    double inv = rsqrt(nn);
    v[0] = vx * inv; v[1] = vy * inv; v[2] = vz * inv;
}

// ============================ primary path =================================
#define P1_BLOCK 1024
#define P1_ITEMS 8     // voxels per thread per round -> 8192 per block-round
#define P1_ROUND (P1_BLOCK * P1_ITEMS)

__global__ __launch_bounds__(P1_BLOCK) void p1_bucket(
        const float* __restrict__ data,
        const int* __restrict__ cid,
        unsigned int* __restrict__ gcnt,     // [nbuckets]
        float4* __restrict__ bbuf,           // [nb*CAP2]
        unsigned char* __restrict__ lcb,     // [nb*CAP2] 6-bit tags
        int n_vox, int nbuckets) {
    __shared__ float4 ss[P1_ROUND];          // 128 KB sorted round buffer
    __shared__ unsigned int hist[NB_MAX];    // 4 KB
    __shared__ unsigned int lbase[NB_MAX];   // 4 KB  exclusive scan
    __shared__ unsigned int gbase[NB_MAX];   // 4 KB  global bases
    const int tid = threadIdx.x;
    const int total_rounds = (n_vox + P1_ROUND - 1) / P1_ROUND;

    for (int r = blockIdx.x; r < total_rounds; r += gridDim.x) {
        const int start = r * P1_ROUND;
        const int rtotal = min(P1_ROUND, n_vox - start);
        for (int j = tid; j < nbuckets; j += P1_BLOCK) hist[j] = 0;
        __syncthreads();

        int   bk[P1_ITEMS];
        int   cd[P1_ITEMS];
        float px[P1_ITEMS], py[P1_ITEMS], pz[P1_ITEMS];
        unsigned int rk[P1_ITEMS];
#pragma unroll
        for (int k = 0; k < P1_ITEMS; ++k) {
            int i = start + tid + k * P1_BLOCK;   // coalesced lane pattern
            if (i < n_vox) {
                int c = cid[i];
                cd[k] = c;
                bk[k] = c >> 6;
                const float* row = data + (size_t)i * 6;
                px[k] = row[1]; py[k] = row[2]; pz[k] = row[3];
                rk[k] = atomicAdd(&hist[bk[k]], 1u);   // local rank
            } else {
                bk[k] = -1;
            }
        }
        __syncthreads();

        // exclusive scan of hist -> lbase (Hillis-Steele over nbuckets)
        for (int j = tid; j < nbuckets; j += P1_BLOCK) lbase[j] = hist[j];
        __syncthreads();
        for (int off = 1; off < nbuckets; off <<= 1) {
            unsigned int v = 0;
            for (int j = tid; j < nbuckets; j += P1_BLOCK)
                v = (j >= off) ? lbase[j - off] : 0u;   // P1_BLOCK>=nbuckets: single j
            __syncthreads();
            for (int j = tid; j < nbuckets; j += P1_BLOCK)
                if (j >= off) lbase[j] += v;
            __syncthreads();
        }
        for (int j = tid; j < nbuckets; j += P1_BLOCK) {
            unsigned int h = hist[j];
            lbase[j] -= h;                       // inclusive -> exclusive
            gbase[j] = h ? atomicAdd(&gcnt[j], h) : 0u;
        }
        __syncthreads();

        // scatter the round into LDS in bucket-sorted order
#pragma unroll
        for (int k = 0; k < P1_ITEMS; ++k) {
            if (bk[k] >= 0) {
                unsigned int p = lbase[bk[k]] + rk[k];
                ss[p] = make_float4(px[k], py[k], pz[k], __int_as_float(cd[k]));
            }
        }
        __syncthreads();

        // linear write-out: consecutive lanes -> consecutive positions
        for (int j = tid; j < rtotal; j += P1_BLOCK) {
            float4 p = ss[j];
            int c  = __float_as_int(p.w);
            int bb = c >> 6;
            unsigned int off = gbase[bb] + ((unsigned)j - lbase[bb]);
            if (off < (unsigned int)CAP2) {
                bbuf[(size_t)bb * CAP2 + off] = p;   // p2 masks .w with &63
                lcb[(size_t)bb * CAP2 + off] = (unsigned char)(c & (NB_CL - 1));
            }
        }
        __syncthreads();
    }
}

__global__ __launch_bounds__(512) void p2_features(
        const unsigned int* __restrict__ gcnt,
        const float4* __restrict__ bbuf,
        const unsigned char* __restrict__ lcb,
        float* __restrict__ out, int C) {
    __shared__ float sx[CAP2];                  // 24 KB  sorted x
    __shared__ float sy[CAP2];                  // 24 KB  sorted y
    __shared__ float sz[CAP2];                  // 24 KB  sorted z
    __shared__ unsigned int hist[NB_CL];
    __shared__ unsigned int basex[NB_CL];
    __shared__ unsigned int hist2[NB_CL];

    const int b   = blockIdx.x;
    const int tid = threadIdx.x;
    const int bcnt = min((int)gcnt[b], CAP2);
    const float4* src = bbuf + (size_t)b * CAP2;
    const unsigned char* lc8 = lcb + (size_t)b * CAP2;

    if (tid < NB_CL) { hist[tid] = 0; hist2[tid] = 0; }
    __syncthreads();

    // ---- pass A: histogram from compact tag bytes (16 tags / uint4 load) ----
    {
        const uint4* tg16 = reinterpret_cast<const uint4*>(lc8);
        const int n16 = (bcnt + 15) >> 4;
        for (int g = tid; g < n16; g += 512) {
            uint4 t = tg16[g];
            const int base16 = g << 4;
            unsigned int wd0 = t.x, wd1 = t.y, wd2 = t.z, wd3 = t.w;
#pragma unroll
            for (int bb2 = 0; bb2 < 4; ++bb2) {
                int i0 = base16 + bb2;
                if (i0 < bcnt) atomicAdd(&hist[(wd0 >> (8 * bb2)) & (NB_CL - 1)], 1u);
            }
#pragma unroll
            for (int bb2 = 0; bb2 < 4; ++bb2) {
                int i1 = base16 + 4 + bb2;
                if (i1 < bcnt) atomicAdd(&hist[(wd1 >> (8 * bb2)) & (NB_CL - 1)], 1u);
            }
#pragma unroll
            for (int bb2 = 0; bb2 < 4; ++bb2) {
                int i2 = base16 + 8 + bb2;
                if (i2 < bcnt) atomicAdd(&hist[(wd2 >> (8 * bb2)) & (NB_CL - 1)], 1u);
            }
#pragma unroll
            for (int bb2 = 0; bb2 < 4; ++bb2) {
                int i3 = base16 + 12 + bb2;
                if (i3 < bcnt) atomicAdd(&hist[(wd3 >> (8 * bb2)) & (NB_CL - 1)], 1u);
            }
        }
    }
    __syncthreads();

    // ---- exclusive scan over 64 entries (wave 0 shfl scan) ----
    if (tid < NB_CL) {
        unsigned int h = hist[tid];
        unsigned int inc = h;
#pragma unroll
        for (int off = 1; off < NB_CL; off <<= 1) {
            unsigned int t = __shfl_up(inc, off);
            if (tid >= off) inc += t;
        }
        basex[tid] = inc - h;
    }
    __syncthreads();

    // ---- pass B: sorted placement into LDS, ILP x4 (single float4 stream) ----
    for (int base_i = 0; base_i < bcnt; base_i += 2048) {
        int i0 = base_i + tid, i1 = i0 + 512, i2 = i0 + 1024, i3 = i0 + 1536;
        bool v0 = i0 < bcnt, v1 = i1 < bcnt, v2 = i2 < bcnt, v3 = i3 < bcnt;
        float4 p0, p1, p2, p3;
        if (v0) p0 = src[i0];
        if (v1) p1 = src[i1];
        if (v2) p2 = src[i2];
        if (v3) p3 = src[i3];
        if (v0) { int c = __float_as_int(p0.w) & (NB_CL - 1); unsigned r = atomicAdd(&hist2[c], 1u); unsigned q = basex[c] + r; sx[q] = p0.x; sy[q] = p0.y; sz[q] = p0.z; }
        if (v1) { int c = __float_as_int(p1.w) & (NB_CL - 1); unsigned r = atomicAdd(&hist2[c], 1u); unsigned q = basex[c] + r; sx[q] = p1.x; sy[q] = p1.y; sz[q] = p1.z; }
        if (v2) { int c = __float_as_int(p2.w) & (NB_CL - 1); unsigned r = atomicAdd(&hist2[c], 1u); unsigned q = basex[c] + r; sx[q] = p2.x; sy[q] = p2.y; sz[q] = p2.z; }
        if (v3) { int c = __float_as_int(p3.w) & (NB_CL - 1); unsigned r = atomicAdd(&hist2[c], 1u); unsigned q = basex[c] + r; sx[q] = p3.x; sy[q] = p3.y; sz[q] = p3.z; }
    }
    __syncthreads();

    // ---- barrier-free per-wave tail: 8 clusters per wave ----
    const int w    = tid >> 6;     // 0..7
    const int lane = tid & 63;

    float k0 = 0.f, k1 = 0.f, k2 = 0.f, k3 = 0.f, k4 = 0.f;
    float k5 = 0.f, k6 = 0.f, k7 = 0.f, k8 = 0.f;

#pragma unroll
    for (int jj = 0; jj < 8; ++jj) {
        const int lc = (w << 3) | jj;
        const int n  = (int)hist[lc];
        const unsigned int nb = basex[lc];
        float s0 = 0.f, s1 = 0.f, s2 = 0.f, s3 = 0.f, s4 = 0.f;
        float s5 = 0.f, s6 = 0.f, s7 = 0.f, s8 = 0.f;
        for (int j = lane; j < n; j += 64) {
            float x = sx[nb + j], y = sy[nb + j], z = sz[nb + j];
            s0 += x;     s1 += y;     s2 += z;
            s3 += x * x; s4 += x * y; s5 += x * z;
            s6 += y * y; s7 += y * z; s8 += z * z;
        }
#pragma unroll
        for (int d = 32; d > 0; d >>= 1) {
            s0 += __shfl_xor(s0, d); s1 += __shfl_xor(s1, d); s2 += __shfl_xor(s2, d);
            s3 += __shfl_xor(s3, d); s4 += __shfl_xor(s4, d); s5 += __shfl_xor(s5, d);
            s6 += __shfl_xor(s6, d); s7 += __shfl_xor(s7, d); s8 += __shfl_xor(s8, d);
        }
        if (lane == jj) {
            k0 = s0; k1 = s1; k2 = s2; k3 = s3; k4 = s4;
            k5 = s5; k6 = s6; k7 = s7; k8 = s8;
        }
    }

    // ---- 8 f64 eigens on lanes 0..7 of this wave ----
    float cenx = 0.f, ceny = 0.f, cenz = 0.f;
    float evx = 0.f, evy = 0.f, evz = 0.f, fdw = 0.f;
    if (lane < 8) {
        const int lc = (w << 3) | lane;
        const int cl = b * NB_CL + lc;
        const int n  = (int)hist[lc];
        double dn = (double)n;
        double nd = (double)max(n, 1);
        double cx = (double)k0 / nd;
        double cy = (double)k1 / nd;
        double cz = (double)k2 / nd;

        double axx = (double)k3 - dn * cx * cx;
        double axy = (double)k4 - dn * cx * cy;
        double axz = (double)k5 - dn * cx * cz;
        double ayy = (double)k6 - dn * cy * cy;
        double ayz = (double)k7 - dn * cy * cz;
        double azz = (double)k8 - dn * cz * cz;

        double w0, w1, w2, v[3];
        eig3_sym(axx, axy, axz, ayy, ayz, azz, w0, w1, w2, v);

        double safe_w2 = (w2 > 0.0) ? w2 : 1.0;
        double isw = 1.0 / safe_w2;
        bool multi = (n >= 2);

        cenx = (float)cx; ceny = (float)cy; cenz = (float)cz;
        evx = (float)v[0]; evy = (float)v[1]; evz = (float)v[2];
        fdw = (float)(1.0 - w1 / safe_w2);

        if (cl < C) {
            float b3  = multi ? (float)(axx * isw) : 0.0f;
            float b4  = multi ? (float)(axy * isw) : 0.0f;
            float b5  = multi ? (float)(axz * isw) : 0.0f;
            float b7  = multi ? (float)(ayy * isw) : 0.0f;
            float b8  = multi ? (float)(ayz * isw) : 0.0f;
            float b11 = multi ? (float)(azz * isw) : 0.0f;
            float4* o = (float4*)(out + (size_t)cl * 16);
            o[0] = make_float4(cenx, ceny, cenz, b3);
            o[1] = make_float4(b4, b5, b4, b7);
            o[2] = make_float4(b8, b5, b8, b11);
        }
    }

    // ---- sc pass: shfl broadcast from lane jj, linear LDS reads ----
#pragma unroll 1
    for (int jj = 0; jj < 8; ++jj) {
        const int lc = (w << 3) | jj;
        const int cl = b * NB_CL + lc;
        if (cl >= C) continue;                  // wave-uniform
        const int n = (int)hist[lc];
        const unsigned int nb = basex[lc];
        const float fcx = __shfl(cenx, jj), fcy = __shfl(ceny, jj), fcz = __shfl(cenz, jj);
        const float vx = __shfl(evx, jj), vy = __shfl(evy, jj), vz = __shfl(evz, jj);
        const float dwv = __shfl(fdw, jj);
        float sc = 0.0f;
        for (int j = lane; j < n; j += 64) {
            float x = sx[nb + j] - fcx, y = sy[nb + j] - fcy, z = sz[nb + j] - fcz;
            float x0 = x * vx + y * vy + z * vz;
            float qx = x - x0 * vx, qy = y - x0 * vy, qz = z - x0 * vz;
            sc += x0 * sqrtf(qx * qx + qy * qy + qz * qz);
        }
#pragma unroll
        for (int d = 32; d > 0; d >>= 1) sc += __shfl_xor(sc, d);

        if (lane == 0) {
            float sgn = (sc < 0.0f) ? -1.0f : 1.0f;
            float m = (n >= 2) ? sgn * dwv : 0.0f;
            ((float4*)(out + (size_t)cl * 16))[3] =
                make_float4(vx * m, vy * m, vz * m, (float)n);
        }
    }
}

// ============================ fallback path (round-2) ======================
#define FXP_SCALE 131072.0f
#define FXP_BIAS  4194304
#define FXP_INV   (1.0 / 131072.0)

__device__ __forceinline__ unsigned int fxp_enc(float v) {
    return (unsigned int)(__float2int_rn(v * FXP_SCALE) + FXP_BIAS);
}
__device__ __forceinline__ double fxp_dec(unsigned int s, int n) {
    return (double)((long long)s - (long long)n * FXP_BIAS) * FXP_INV;
}

__global__ void k1_accum(const float* __restrict__ data,
                         const int* __restrict__ cid,
                         unsigned long long* __restrict__ acc,
                         int n_vox) {
    int stride = gridDim.x * blockDim.x;
    for (int i = blockIdx.x * blockDim.x + threadIdx.x; i < n_vox; i += stride) {
        int c = cid[i];
        const float* row = data + (size_t)i * 6;
        float x = row[1], y = row[2], z = row[3];
        unsigned long long* a = acc + (size_t)c * 5;
        unsigned long long p0 = ((unsigned long long)fxp_enc(y)     << 32) | fxp_enc(x);
        unsigned long long p1 = ((unsigned long long)fxp_enc(x * x) << 32) | fxp_enc(z);
        unsigned long long p2 = ((unsigned long long)fxp_enc(x * z) << 32) | fxp_enc(x * y);
        unsigned long long p3 = ((unsigned long long)fxp_enc(y * z) << 32) | fxp_enc(y * y);
        unsigned long long p4 = (1ULL << 32)                               | fxp_enc(z * z);
        atomicAdd(&a[0], p0);
        atomicAdd(&a[1], p1);
        atomicAdd(&a[2], p2);
        atomicAdd(&a[3], p3);
        atomicAdd(&a[4], p4);
    }
}

__global__ void k2_cluster(const unsigned long long* __restrict__ acc,
                           float* __restrict__ wf,
                           float* __restrict__ out, int C) {
    int c = blockIdx.x * blockDim.x + threadIdx.x;
    if (c >= C) return;
    const unsigned long long* a = acc + (size_t)c * 5;
    unsigned long long s0 = a[0], s1 = a[1], s2 = a[2], s3 = a[3], s4 = a[4];
    int n = (int)(s4 >> 32);

    double sx  = fxp_dec((unsigned int)s0,         n);
    double sy  = fxp_dec((unsigned int)(s0 >> 32), n);
    double sz  = fxp_dec((unsigned int)s1,         n);
    double sxx = fxp_dec((unsigned int)(s1 >> 32), n);
    double sxy = fxp_dec((unsigned int)s2,         n);
    double sxz = fxp_dec((unsigned int)(s2 >> 32), n);
    double syy = fxp_dec((unsigned int)s3,         n);
    double syz = fxp_dec((unsigned int)(s3 >> 32), n);
    double szz = fxp_dec((unsigned int)s4,         n);

    double nd = (double)max(n, 1);
    double cx = sx / nd, cy = sy / nd, cz = sz / nd;
    double dn = (double)n;
    double axx = sxx - dn * cx * cx;
    double axy = sxy - dn * cx * cy;
    double axz = sxz - dn * cx * cz;
    double ayy = syy - dn * cy * cy;
    double ayz = syz - dn * cy * cz;
    double azz = szz - dn * cz * cz;

    double w0, w1, w2, v[3];
    eig3_sym(axx, axy, axz, ayy, ayz, azz, w0, w1, w2, v);

    double safe_w2 = (w2 > 0.0) ? w2 : 1.0;
    double dirwt   = 1.0 - w1 / safe_w2;
    double isw     = 1.0 / safe_w2;
    bool multi = (n >= 2);

    float* o = out + (size_t)c * 16;
    o[0] = (float)cx; o[1] = (float)cy; o[2] = (float)cz;
    if (multi) {
        o[3]  = (float)(axx * isw); o[4]  = (float)(axy * isw); o[5]  = (float)(axz * isw);
        o[6]  = (float)(axy * isw); o[7]  = (float)(ayy * isw); o[8]  = (float)(ayz * isw);
        o[9]  = (float)(axz * isw); o[10] = (float)(ayz * isw); o[11] = (float)(azz * isw);
    } else {
        o[3] = 0.f; o[4] = 0.f; o[5] = 0.f; o[6] = 0.f; o[7] = 0.f;
        o[8] = 0.f; o[9] = 0.f; o[10] = 0.f; o[11] = 0.f;
    }
    o[15] = (float)n;

    wf[(size_t)C * 1 + c] = (float)cx;
    wf[(size_t)C * 2 + c] = (float)cy;
    wf[(size_t)C * 3 + c] = (float)cz;
    wf[(size_t)C * 4 + c] = (float)v[0];
    wf[(size_t)C * 5 + c] = (float)v[1];
    wf[(size_t)C * 6 + c] = (float)v[2];
    wf[(size_t)C * 7 + c] = (float)dirwt;
}

__global__ void k3_sc(const float* __restrict__ data,
                      const int* __restrict__ cid,
                      float* __restrict__ wf,
                      int n_vox, int C) {
    const float* cenx = wf + (size_t)C * 1;
    const float* ceny = wf + (size_t)C * 2;
    const float* cenz = wf + (size_t)C * 3;
    const float* v0x  = wf + (size_t)C * 4;
    const float* v0y  = wf + (size_t)C * 5;
    const float* v0z  = wf + (size_t)C * 6;
    float* sc = wf;
    int stride = gridDim.x * blockDim.x;
    for (int i = blockIdx.x * blockDim.x + threadIdx.x; i < n_vox; i += stride) {
        int c = cid[i];
        const float* row = data + (size_t)i * 6;
        float x = row[1] - cenx[c];
        float y = row[2] - ceny[c];
        float z = row[3] - cenz[c];
        float vx = v0x[c], vy = v0y[c], vz = v0z[c];
        float x0 = x * vx + y * vy + z * vz;
        float px = x - x0 * vx;
        float py = y - x0 * vy;
        float pz = z - x0 * vz;
        atomicAdd(&sc[c], x0 * sqrtf(px * px + py * py + pz * pz));
    }
}

__global__ void k4_final(const unsigned long long* __restrict__ acc,
                         const float* __restrict__ wf,
                         float* __restrict__ out, int C) {
    int c = blockIdx.x * blockDim.x + threadIdx.x;
    if (c >= C) return;
    int n = (int)(acc[(size_t)c * 5 + 4] >> 32);
    float scv = wf[c];
    float vx  = wf[(size_t)C * 4 + c];
    float vy  = wf[(size_t)C * 5 + c];
    float vz  = wf[(size_t)C * 6 + c];
    float dir = wf[(size_t)C * 7 + c];
    float sgn = (scv < 0.0f) ? -1.0f : 1.0f;
    float m = (n >= 2) ? sgn * dir : 0.0f;
    float* o = out + (size_t)c * 16;
    o[12] = vx * m;
    o[13] = vy * m;
    o[14] = vz * m;
}

// ============================ launch =======================================
extern "C" void kernel_launch(void* const* d_in, const int* in_sizes, int n_in,
                              void* d_out, int out_size, void* d_ws, size_t ws_size,
                              hipStream_t stream) {
    const float* data = (const float*)d_in[0];
    const int*   cid  = (const int*)d_in[1];
    float* out = (float*)d_out;

    int n_vox = in_sizes[1];
    int C     = out_size / 16;

    int nbuckets = (C + NB_CL - 1) / NB_CL;
    long long expected = (C > 0) ? (long long)n_vox * NB_CL / C : 0;
    size_t gcnt_bytes = ((size_t)nbuckets * 4 + 255) & ~(size_t)255;
    size_t bbuf_bytes = (size_t)nbuckets * CAP2 * 16;
    size_t need = gcnt_bytes + bbuf_bytes + (size_t)nbuckets * CAP2;

    if (C > 0 && nbuckets <= NB_MAX && expected <= (CAP2 * 7) / 8 && ws_size >= need) {
        unsigned int* gcnt = (unsigned int*)d_ws;
        float4* bbuf = (float4*)((char*)d_ws + gcnt_bytes);
        unsigned char* lcb = (unsigned char*)((char*)d_ws + gcnt_bytes + bbuf_bytes);
        hipMemsetAsync(d_ws, 0, gcnt_bytes, stream);
        int total_rounds = (n_vox + P1_ROUND - 1) / P1_ROUND;
        int p1_blocks = total_rounds < 512 ? total_rounds : 512;
        if (p1_blocks < 1) p1_blocks = 1;
        p1_bucket<<<p1_blocks, P1_BLOCK, 0, stream>>>(data, cid, gcnt, bbuf, lcb, n_vox, nbuckets);
        p2_features<<<nbuckets, 512, 0, stream>>>(gcnt, bbuf, lcb, out, C);
    } else {
        unsigned long long* acc = (unsigned long long*)d_ws;
        float* wf = (float*)((char*)d_ws + (size_t)C * 40);
        hipMemsetAsync(d_ws, 0, (size_t)C * 44, stream);
        const int vox_blocks = 4096;
        const int cl_blocks  = (C + 255) / 256;
        k1_accum<<<vox_blocks, 256, 0, stream>>>(data, cid, acc, n_vox);
        k2_cluster<<<cl_blocks, 256, 0, stream>>>(acc, wf, out, C);
        k3_sc<<<vox_blocks, 256, 0, stream>>>(data, cid, wf, n_vox, C);
        k4_final<<<cl_blocks, 256, 0, stream>>>(acc, wf, out, C);
    }
}